// Round 9
// baseline (1812.410 us; speedup 1.0000x reference)
//
#include <hip/hip_runtime.h>
#include <cstdint>
#include <cstddef>

// ---------------- problem constants ----------------
#define BB 512
#define TT 96
#define FF 128
#define HH 512
#define BTF 6291456      // B*T*F
#define BH  262144       // B*H

typedef unsigned short ushort_t;
typedef __attribute__((ext_vector_type(8))) short bf16x8;
typedef __attribute__((ext_vector_type(4))) float f32x4;

// ---------------- ws layout (bytes) ----------------
static constexpr size_t OFF_FLAGS = 0;                        // 16 barrier counters, 128 B apart
static constexpr size_t OFF_WDXD  = 2048;                     // f32 [F] diag of Wdx
static constexpr size_t OFF_DELTA = 4096;                     // bf16 [T*B*F]
static constexpr size_t OFF_MBF   = OFF_DELTA + 12582912;     // bf16 [B*T*F]
static constexpr size_t OFF_ALPHA = OFF_MBF   + 12582912;     // bf16 [T*B*F]
static constexpr size_t OFF_GH    = OFF_ALPHA + 12582912;     // bf16 [T*B*H]
static constexpr size_t OFF_H     = OFF_GH    + 50331648;     // f32  [2][B*H] ping-pong
static constexpr size_t OFF_HDEC  = OFF_H     + 2097152;      // bf16 [2][B*H]
static constexpr size_t OFF_CCBF  = OFF_HDEC  + 1048576;      // bf16 [B*F]

// ---------------- k_main dynamic LDS layout (bytes) ----------------
// W_fr: fragment-packed gate weights. Slot ((sec*16 + nt*4 + kk)*64 + lane)*16B.
// Sections: 0=Wih cc (k0..128), 1=Wih m (k128..256), 2..5=Whh k(sec-2)*128.
// A wave's ds_read_b128 of one fragment covers 1024 contiguous bytes -> conflict-free.
static constexpr int LDS_W     = 0;          // 6*16*64*16 = 98304
static constexpr int LDS_GATES = 98304;      // 2 x 64 x 68 f32 = 34816
static constexpr int LDS_BIAS  = 133120;     // 64 f32 = 256
static constexpr int LDS_XPART = 133376;     // 16 x 128 f32 = 8192
static constexpr int LDS_XC    = 141568;     // 256 f32 = 1024
static constexpr int LDS_TOTAL = 142592;

// ---------------- helpers ----------------
__device__ __forceinline__ float bf2f(ushort_t u) {
  union { unsigned u; float f; } c; c.u = ((unsigned)u) << 16; return c.f;
}
__device__ __forceinline__ ushort_t f2bf(float f) {
  union { float f; unsigned u; } c; c.f = f;
  unsigned x = c.u;
  unsigned r = (x + 0x7FFFu + ((x >> 16) & 1u)) >> 16;
  return (ushort_t)r;
}
__device__ __forceinline__ float lo2f(unsigned p) {
  union { unsigned u; float f; } c; c.u = p << 16; return c.f;
}
__device__ __forceinline__ float hi2f(unsigned p) {
  union { unsigned u; float f; } c; c.u = p & 0xffff0000u; return c.f;
}
__device__ __forceinline__ float sigm(float v) { return 1.0f / (1.0f + __expf(-v)); }

// Coherent STORES (sc0 sc1, write-through to LLC) — producer side of the exchange.
// Consumer side uses PLAIN CACHED loads, made safe by the ACQUIRE-ordered barrier
// poll in bar_wait (same pattern as cooperative-groups grid.sync): the acquire load
// emits the cache-invalidate sequence, so post-barrier plain loads see fresh data
// AND get L2-deduplicated across the WGs sharing an XCD (32x less LLC traffic).
__device__ __forceinline__ void cstore8(void* p, unsigned long long v) {
  __hip_atomic_store((unsigned long long*)p, v, __ATOMIC_RELAXED, __HIP_MEMORY_SCOPE_AGENT);
}
__device__ __forceinline__ void cstore4(void* p, unsigned v) {
  __hip_atomic_store((unsigned*)p, v, __ATOMIC_RELAXED, __HIP_MEMORY_SCOPE_AGENT);
}
__device__ __forceinline__ void cstore2(ushort_t* p, ushort_t v) {
  __hip_atomic_store(p, v, __ATOMIC_RELAXED, __HIP_MEMORY_SCOPE_AGENT);
}
__device__ __forceinline__ void cstoref(float* p, float v) {
  union { float f; unsigned u; } c; c.f = v;
  cstore4(p, c.u);
}
__device__ __forceinline__ float rdlane_f(float v, int sl) {
  return __int_as_float(__builtin_amdgcn_readlane(__float_as_int(v), sl));
}

// ---------------- precompute: flag zero + Wdx diag ----------------
__global__ void k_cvt(const float* __restrict__ Wdx, char* __restrict__ ws) {
  int tid = threadIdx.x;
  unsigned* fl = (unsigned*)(ws + OFF_FLAGS);
  fl[tid] = 0; fl[256 + tid] = 0;
  float* wdxd = (float*)(ws + OFF_WDXD);
  if (tid < FF) wdxd[tid] = Wdx[tid * (FF + 1)];
}

// ---------------- precompute: delta recurrence + m bf16 ----------------
__global__ void k_prep(const int* __restrict__ mask, char* __restrict__ ws) {
  ushort_t* delta = (ushort_t*)(ws + OFF_DELTA);
  ushort_t* mbf   = (ushort_t*)(ws + OFF_MBF);
  int gtid = blockIdx.x * 256 + threadIdx.x;   // 65536 = B*F
  int b = gtid >> 7, f = gtid & 127;
  const int* mrow = mask + (size_t)b * (TT * FF) + f;
  float dprev = 0.0f;
  for (int t = 0; t < TT; ++t) {
    float d;
    if (t == 0) d = 0.0f;
    else {
      int mp = mrow[(t - 1) * FF];
      d = mp ? 1.0f : dprev + 1.0f;
    }
    dprev = d;
    delta[((size_t)t * BB + b) * FF + f] = f2bf(d);
    int mc = mrow[t * FF];
    mbf[(size_t)b * (TT * FF) + t * FF + f] = f2bf((float)mc);
  }
}

// ---------------- precompute: gamma_h = exp(-relu(delta @ Wdh^T + bdh)) ----------------
__global__ __launch_bounds__(256, 4) void k_gh(const float* __restrict__ Wdh,
                                               const float* __restrict__ bdh,
                                               char* __restrict__ ws) {
  __shared__ ushort_t A_lds[64 * 136];
  __shared__ ushort_t B_lds[64 * 136];
  const ushort_t* delta = (const ushort_t*)(ws + OFF_DELTA);
  ushort_t* gh = (ushort_t*)(ws + OFF_GH);
  int tid = threadIdx.x;
  int m0 = blockIdx.x * 64;
  int n0 = blockIdx.y * 64;
  for (int v = tid; v < 1024; v += 256) {
    int row = v >> 4, seg = v & 15;
    *(uint4*)&A_lds[row * 136 + seg * 8] =
        *(const uint4*)(delta + ((size_t)(m0 + row)) * FF + seg * 8);
  }
  for (int v = tid; v < 1024; v += 256) {
    int n = v >> 4, seg = v & 15;
    const float* src = Wdh + (size_t)(n0 + n) * FF + seg * 8;
    ushort_t tmp[8];
#pragma unroll
    for (int j = 0; j < 8; ++j) tmp[j] = f2bf(src[j]);
    *(uint4*)&B_lds[n * 136 + seg * 8] = *(const uint4*)tmp;
  }
  __syncthreads();
  int wave = tid >> 6, lane = tid & 63, quad = lane >> 4, lan = lane & 15;
  int mt = wave;
  f32x4 acc[4];
#pragma unroll
  for (int nt = 0; nt < 4; ++nt) acc[nt] = (f32x4){0.f, 0.f, 0.f, 0.f};
  const ushort_t* ab = &A_lds[(mt * 16 + lan) * 136 + quad * 8];
#pragma unroll
  for (int kk = 0; kk < 4; ++kk) {
    bf16x8 af = *(const bf16x8*)(ab + kk * 32);
#pragma unroll
    for (int nt = 0; nt < 4; ++nt) {
      bf16x8 bfv = *(const bf16x8*)(&B_lds[(nt * 16 + lan) * 136 + kk * 32 + quad * 8]);
      acc[nt] = __builtin_amdgcn_mfma_f32_16x16x32_bf16(af, bfv, acc[nt], 0, 0, 0);
    }
  }
#pragma unroll
  for (int nt = 0; nt < 4; ++nt) {
#pragma unroll
    for (int r = 0; r < 4; ++r) {
      int mg = m0 + mt * 16 + quad * 4 + r;
      int nc = n0 + nt * 16 + lan;
      float v = acc[nt][r] + bdh[nc];
      gh[(size_t)mg * HH + nc] = f2bf(__expf(-fmaxf(v, 0.0f)));
    }
  }
}

// ---------------- precompute: alpha = sigmoid([gamma_x, m] @ Wc^T + bc) ----------------
__global__ __launch_bounds__(256, 4) void k_al(const float* __restrict__ Wc,
                                               const float* __restrict__ bc,
                                               const float* __restrict__ bdx,
                                               char* __restrict__ ws) {
  __shared__ ushort_t A_lds[64 * 136];
  __shared__ ushort_t B_lds[64 * 136];
  const ushort_t* delta = (const ushort_t*)(ws + OFF_DELTA);
  const ushort_t* mbf   = (const ushort_t*)(ws + OFF_MBF);
  const float* wdxd     = (const float*)(ws + OFF_WDXD);
  ushort_t* alpha = (ushort_t*)(ws + OFF_ALPHA);
  int tid = threadIdx.x;
  int m0 = blockIdx.x * 64;
  int n0 = blockIdx.y * 64;
  int wave = tid >> 6, lane = tid & 63, quad = lane >> 4, lan = lane & 15;
  int mt = wave;
  f32x4 acc[4];
#pragma unroll
  for (int nt = 0; nt < 4; ++nt) acc[nt] = (f32x4){0.f, 0.f, 0.f, 0.f};
  for (int c = 0; c < 2; ++c) {
    __syncthreads();
    if (c == 0) {
      for (int v = tid; v < 1024; v += 256) {
        int row = v >> 4, seg = v & 15;
        int mg = m0 + row;
        ushort_t tmp[8];
#pragma unroll
        for (int j = 0; j < 8; ++j) {
          int k = seg * 8 + j;
          float d = bf2f(delta[(size_t)mg * FF + k]);
          float g = __expf(-fmaxf(fmaf(d, wdxd[k], bdx[k]), 0.0f));
          tmp[j] = f2bf(g);
        }
        *(uint4*)&A_lds[row * 136 + seg * 8] = *(const uint4*)tmp;
      }
    } else {
      for (int v = tid; v < 1024; v += 256) {
        int row = v >> 4, seg = v & 15;
        int mg = m0 + row;
        int t = mg >> 9, b = mg & 511;
        *(uint4*)&A_lds[row * 136 + seg * 8] =
            *(const uint4*)(mbf + ((size_t)b * TT + t) * FF + seg * 8);
      }
    }
    for (int v = tid; v < 1024; v += 256) {
      int n = v >> 4, seg = v & 15;
      const float* src = Wc + (size_t)(n0 + n) * 256 + c * 128 + seg * 8;
      ushort_t tmp[8];
#pragma unroll
      for (int j = 0; j < 8; ++j) tmp[j] = f2bf(src[j]);
      *(uint4*)&B_lds[n * 136 + seg * 8] = *(const uint4*)tmp;
    }
    __syncthreads();
    const ushort_t* ab = &A_lds[(mt * 16 + lan) * 136 + quad * 8];
#pragma unroll
    for (int kk = 0; kk < 4; ++kk) {
      bf16x8 af = *(const bf16x8*)(ab + kk * 32);
#pragma unroll
      for (int nt = 0; nt < 4; ++nt) {
        bf16x8 bfv = *(const bf16x8*)(&B_lds[(nt * 16 + lan) * 136 + kk * 32 + quad * 8]);
        acc[nt] = __builtin_amdgcn_mfma_f32_16x16x32_bf16(af, bfv, acc[nt], 0, 0, 0);
      }
    }
  }
#pragma unroll
  for (int nt = 0; nt < 4; ++nt) {
#pragma unroll
    for (int r = 0; r < 4; ++r) {
      int mg = m0 + mt * 16 + quad * 4 + r;
      int nc = n0 + nt * 16 + lan;
      float v = acc[nt][r] + bc[nc];
      alpha[(size_t)mg * FF + nc] = f2bf(sigm(v));
    }
  }
}

// ---------------- split group barrier ----------------
// Arrive: __syncthreads drains vmcnt (sc0sc1 stores committed at LLC), then relaxed
// AGENT add (proven protocol). Wait: tid0 polls with an ACQUIRE atomic load (the
// compiler emits the cache-invalidate sequence on it — same pattern as cooperative
// groups grid.sync), then __syncthreads broadcasts the acquire to the WG ->
// subsequent PLAIN loads of exchange arrays are fresh and L2-cacheable.
__device__ __forceinline__ void bar_arrive(unsigned* cnt) {
  __syncthreads();
  if (threadIdx.x == 0)
    __hip_atomic_fetch_add(cnt, 1u, __ATOMIC_RELAXED, __HIP_MEMORY_SCOPE_AGENT);
}
__device__ __forceinline__ void bar_wait(unsigned* cnt, unsigned target) {
  if (threadIdx.x == 0) {
    while (__hip_atomic_load(cnt, __ATOMIC_ACQUIRE, __HIP_MEMORY_SCOPE_AGENT) < target)
      __builtin_amdgcn_s_sleep(1);
  }
  __syncthreads();
}

// ---------------- persistent cooperative kernel: 96-step recurrence ----------------
// grid 256 x 512 threads; dyn LDS 142592 B (1 WG/CU).
// Groups of 32 WGs by (wg & 7). Group g owns batch rows 64g..64g+63. Member m = wg>>3:
//   phase1: rows r0 = 64g + 2m (Wh/Wf in registers, readlane broadcast)
//   phase2: gate col-block ng = m, waves K-split (khalf).
//   Gate weights in FRAGMENT-PACKED LDS (W_fr): conflict-free ds_read_b128.
// Exchange arrays (hws, hdws, ccbf): sc0sc1 STORES + plain CACHED loads under the
// acquire barrier -> per-XCD L2 dedup of the 32x redundant member reads.
__global__ __launch_bounds__(512, 2) void k_main(
    const float* __restrict__ x, const int* __restrict__ mask,
    const float* __restrict__ Wh, const float* __restrict__ Wf,
    const float* __restrict__ bh, const float* __restrict__ bfr,
    const float* __restrict__ Wih, const float* __restrict__ Whh,
    const float* __restrict__ bih, const float* __restrict__ bhh,
    float* __restrict__ out, char* __restrict__ ws) {
  extern __shared__ char smem[];
  ushort_t* W_fr     = (ushort_t*)(smem + LDS_W);
  float* gates_lds   = (float*)(smem + LDS_GATES);
  float* bias_lds    = (float*)(smem + LDS_BIAS);
  float* xh_part     = (float*)(smem + LDS_XPART);
  float* xc_s        = (float*)(smem + LDS_XC);

  unsigned* cnts = (unsigned*)(ws + OFF_FLAGS);
  const ushort_t* alpha = (const ushort_t*)(ws + OFF_ALPHA);
  const ushort_t* gh    = (const ushort_t*)(ws + OFF_GH);
  const ushort_t* mbf   = (const ushort_t*)(ws + OFF_MBF);
  float*    hws  = (float*)(ws + OFF_H);
  ushort_t* hdws = (ushort_t*)(ws + OFF_HDEC);
  ushort_t* ccbf = (ushort_t*)(ws + OFF_CCBF);

  const int tid  = threadIdx.x;
  const int wg   = blockIdx.x;
  const int g    = wg & 7;          // group (XCD-locality heuristic only)
  const int mwg  = wg >> 3;         // member 0..31
  const int ng   = mwg;             // gate col-block
  const int wave = tid >> 6, lane = tid & 63, quad = lane >> 4, lan = lane & 15;
  const int mt = wave & 3, khalf = wave >> 2;
  const int r0 = g * 64 + mwg * 2;  // phase1 rows
  const int arow = g * 64 + mt * 16 + lan;   // phase2 A-fragment batch row

  unsigned* cntA = cnts + (g * 2 + 0) * 32;
  unsigned* cntB = cnts + (g * 2 + 1) * 32;

  // ---- init: gate-weight slice -> fragment-packed LDS (bf16) ----
  for (int q = tid; q < 6144; q += 512) {
    int sec = q >> 10, rem = q & 1023;
    int f = rem >> 6, lw = rem & 63;
    int nt = f >> 2, kk = f & 3;
    int lan_ = lw & 15, quad_ = lw >> 4;
    int r = nt * 512 + ng * 16 + lan_;
    const float* src = (sec < 2)
        ? (Wih + (size_t)r * 256 + sec * 128 + kk * 32 + quad_ * 8)
        : (Whh + (size_t)r * 512 + (sec - 2) * 128 + kk * 32 + quad_ * 8);
    float4 v0 = *(const float4*)src;
    float4 v1 = *(const float4*)(src + 4);
    ushort_t t8[8] = { f2bf(v0.x), f2bf(v0.y), f2bf(v0.z), f2bf(v0.w),
                       f2bf(v1.x), f2bf(v1.y), f2bf(v1.z), f2bf(v1.w) };
    *(uint4*)&W_fr[q * 8] = *(const uint4*)t8;
  }
  if (tid < 64) {
    int r = (tid >> 4) * 512 + ng * 16 + (tid & 15);
    bias_lds[tid] = bih[r] + bhh[r];
  }

#define WFRAG(sec, nt, kk) (*(const bf16x8*)&W_fr[((((sec) * 16 + (nt) * 4 + (kk)) * 64 + lane)) * 8])

  // ---- init: Wh / Wf slices -> registers ----
  unsigned wh_p[64];
  {
    const float* s0 = Wh + (size_t)lane * HH + 64 * wave;
    const float* s1 = Wh + (size_t)(lane + 64) * HH + 64 * wave;
#pragma unroll
    for (int i4 = 0; i4 < 16; ++i4) {
      float4 a = *(const float4*)(s0 + i4 * 4);
      float4 b = *(const float4*)(s1 + i4 * 4);
      wh_p[i4 * 4 + 0] = ((unsigned)f2bf(a.x)) | (((unsigned)f2bf(b.x)) << 16);
      wh_p[i4 * 4 + 1] = ((unsigned)f2bf(a.y)) | (((unsigned)f2bf(b.y)) << 16);
      wh_p[i4 * 4 + 2] = ((unsigned)f2bf(a.z)) | (((unsigned)f2bf(b.z)) << 16);
      wh_p[i4 * 4 + 3] = ((unsigned)f2bf(a.w)) | (((unsigned)f2bf(b.w)) << 16);
    }
  }
  unsigned wf_p[16];
  {
    const float* s0 = Wf + (size_t)lane * FF + 16 * wave;
    const float* s1 = Wf + (size_t)(lane + 64) * FF + 16 * wave;
#pragma unroll
    for (int i4 = 0; i4 < 4; ++i4) {
      float4 a = *(const float4*)(s0 + i4 * 4);
      float4 b = *(const float4*)(s1 + i4 * 4);
      wf_p[i4 * 4 + 0] = ((unsigned)f2bf(a.x)) | (((unsigned)f2bf(b.x)) << 16);
      wf_p[i4 * 4 + 1] = ((unsigned)f2bf(a.y)) | (((unsigned)f2bf(b.y)) << 16);
      wf_p[i4 * 4 + 2] = ((unsigned)f2bf(a.z)) | (((unsigned)f2bf(b.z)) << 16);
      wf_p[i4 * 4 + 3] = ((unsigned)f2bf(a.w)) | (((unsigned)f2bf(b.w)) << 16);
    }
  }
  const int fdot = tid & 127;        // scalar-chain output index (tid<256 lanes)
  float bh_r = 0.f, bfr_r = 0.f, wfd_r = 0.f;
  if (tid < 256) {
    bh_r  = bh[fdot];
    bfr_r = bfr[fdot];
    wfd_r = bf2f(f2bf(Wf[(size_t)fdot * FF + fdot]));  // matches bf16 dot term exactly
  }

  // ---- init: zero owned state slices (buffer 0, coherent stores) ----
  const int b_l = tid >> 3, jl0 = 2 * (tid & 7);     // epilogue mapping
  const int bglob = g * 64 + b_l, j0 = ng * 16 + jl0;
  cstore8(&hws[(size_t)bglob * HH + j0], 0ull);
  cstore4(&hdws[(size_t)bglob * HH + j0], 0u);
  float c_r0 = 0.f, c_r1 = 0.f;

  unsigned epA = 0, epB = 1;
  bar_arrive(cntB);

  for (int t = 0; t < TT; ++t) {
    // ---- prefetch step-indexed inputs (read-only, normal cached loads) ----
    float xv = 0.f, mv = 0.f, al = 0.f;
    if (tid < 256) {
      int bl = tid >> 7;
      int b = r0 + bl;
      size_t gix = (size_t)b * (TT * FF) + (size_t)t * FF + fdot;
      xv = x[gix];
      mv = (float)mask[gix];
      al = bf2f(alpha[((size_t)t * BB + b) * FF + fdot]);
    }
    unsigned gh2 = 0;
    if (t < TT - 1)
      gh2 = *(const unsigned*)&gh[((size_t)(t + 1) * BB + bglob) * HH + j0];
    bf16x8 A0[4], A1[4], A2[4];
    if (khalf == 0) {                                   // m-chunk: precomputed, cached
      const ushort_t* mrow = mbf + ((size_t)arow * TT + t) * FF + quad * 8;
#pragma unroll
      for (int kk = 0; kk < 4; ++kk) A0[kk] = *(const bf16x8*)(mrow + kk * 32);
    }

    // ---- wait for h/hdec of this step (acquire barrier releases plain loads) ----
    bar_wait(cntB, 32u * epB);

    // ---- PLAIN cached loads (L2-deduped per XCD): h + hdec A-fragments ----
    const float* hbuf = hws + (size_t)(t & 1) * BH;
    float h0r = hbuf[(size_t)r0 * HH + 64 * wave + lane];
    float h1r = hbuf[(size_t)(r0 + 1) * HH + 64 * wave + lane];
    {
      const ushort_t* hdec = hdws + (size_t)(t & 1) * BH;
      const ushort_t* hrow = hdec + (size_t)arow * HH + quad * 8;
      if (khalf == 0) {
#pragma unroll
        for (int kk = 0; kk < 4; ++kk) A1[kk] = *(const bf16x8*)(hrow + kk * 32);
      } else {
#pragma unroll
        for (int kk = 0; kk < 4; ++kk) A0[kk] = *(const bf16x8*)(hrow + 128 + kk * 32);
#pragma unroll
        for (int kk = 0; kk < 4; ++kk) A1[kk] = *(const bf16x8*)(hrow + 256 + kk * 32);
#pragma unroll
        for (int kk = 0; kk < 4; ++kk) A2[kk] = *(const bf16x8*)(hrow + 384 + kk * 32);
      }
    }

    // ---- phase2a MFMA (K-sections not depending on cc) ----
    f32x4 acc[4];
#pragma unroll
    for (int nt = 0; nt < 4; ++nt) acc[nt] = (f32x4){0.f, 0.f, 0.f, 0.f};
    {
      const int s0 = khalf ? 3 : 1;   // A0: m-chunk (sec1) or hdec c1 (sec3)
      const int s1 = khalf ? 4 : 2;   // A1: hdec c0 (sec2) or c2 (sec4)
#pragma unroll
      for (int kk = 0; kk < 4; ++kk) {
#pragma unroll
        for (int nt = 0; nt < 4; ++nt) {
          acc[nt] = __builtin_amdgcn_mfma_f32_16x16x32_bf16(A0[kk], WFRAG(s0, nt, kk), acc[nt], 0, 0, 0);
        }
      }
#pragma unroll
      for (int kk = 0; kk < 4; ++kk) {
#pragma unroll
        for (int nt = 0; nt < 4; ++nt) {
          acc[nt] = __builtin_amdgcn_mfma_f32_16x16x32_bf16(A1[kk], WFRAG(s1, nt, kk), acc[nt], 0, 0, 0);
        }
      }
      if (khalf == 1) {
#pragma unroll
        for (int kk = 0; kk < 4; ++kk) {
#pragma unroll
          for (int nt = 0; nt < 4; ++nt) {
            acc[nt] = __builtin_amdgcn_mfma_f32_16x16x32_bf16(A2[kk], WFRAG(5, nt, kk), acc[nt], 0, 0, 0);
          }
        }
        // khalf1 waves are done: publish partial gates now
#pragma unroll
        for (int nt = 0; nt < 4; ++nt)
#pragma unroll
          for (int r = 0; r < 4; ++r)
            gates_lds[(64 + mt * 16 + quad * 4 + r) * 68 + nt * 16 + lan] = acc[nt][r];
      }
    }

    // ---- phase1: xh dot, VALU readlane broadcast ----
    {
      float a00 = 0.f, a01 = 0.f, a10 = 0.f, a11 = 0.f;
#pragma unroll
      for (int k = 0; k < 64; ++k) {
        float hk0 = rdlane_f(h0r, k);
        float hk1 = rdlane_f(h1r, k);
        unsigned wp = wh_p[k];
        float w0 = lo2f(wp), w1 = hi2f(wp);
        a00 = fmaf(w0, hk0, a00);
        a10 = fmaf(w1, hk0, a10);
        a01 = fmaf(w0, hk1, a01);
        a11 = fmaf(w1, hk1, a11);
      }
      xh_part[(wave * 2 + 0) * 128 + lane]      = a00;
      xh_part[(wave * 2 + 0) * 128 + 64 + lane] = a10;
      xh_part[(wave * 2 + 1) * 128 + lane]      = a01;
      xh_part[(wave * 2 + 1) * 128 + 64 + lane] = a11;
    }
    __syncthreads();

    float xh_r = 0.f;
    if (tid < 256) {
      int bl = tid >> 7;
      float s = bh_r;
#pragma unroll
      for (int w2 = 0; w2 < 8; ++w2) s += xh_part[(w2 * 2 + bl) * 128 + fdot];
      xh_r = s;
      float xcv = fmaf(1.0f - mv, xh_r, mv * xv);
      xc_s[bl * 128 + fdot] = xcv;
    }
    __syncthreads();

    // ---- z_h dot (same mapping, K-slice of 16 per wave) ----
    {
      float z00 = 0.f, z01 = 0.f, z10 = 0.f, z11 = 0.f;
      float x0 = xc_s[16 * wave + (lane & 15)];
      float x1 = xc_s[128 + 16 * wave + (lane & 15)];
#pragma unroll
      for (int k = 0; k < 16; ++k) {
        float xk0 = rdlane_f(x0, k);
        float xk1 = rdlane_f(x1, k);
        unsigned wp = wf_p[k];
        float w0 = lo2f(wp), w1 = hi2f(wp);
        z00 = fmaf(w0, xk0, z00);
        z10 = fmaf(w1, xk0, z10);
        z01 = fmaf(w0, xk1, z01);
        z11 = fmaf(w1, xk1, z11);
      }
      xh_part[(wave * 2 + 0) * 128 + lane]      = z00;
      xh_part[(wave * 2 + 0) * 128 + 64 + lane] = z10;
      xh_part[(wave * 2 + 1) * 128 + lane]      = z01;
      xh_part[(wave * 2 + 1) * 128 + 64 + lane] = z11;
    }
    __syncthreads();

    float zh = 0.f, ch = 0.f, cc = 0.f;
    if (tid < 256) {
      int bl = tid >> 7;
      int b = r0 + bl;
      float xcv = xc_s[bl * 128 + fdot];
      float s = bfr_r - xcv * wfd_r;
#pragma unroll
      for (int w2 = 0; w2 < 8; ++w2) s += xh_part[(w2 * 2 + bl) * 128 + fdot];
      zh = s;
      ch = fmaf(al, zh, (1.0f - al) * xh_r);
      cc = fmaf(1.0f - mv, ch, mv * xv);
      cstore2(&ccbf[b * FF + fdot], f2bf(cc));          // coherent store: cross-WG consumed
    }

    // ---- barrier A arrive: cc published ----
    bar_arrive(cntA); ++epA;

    // ---- out[] stores overlap barrier-A latency (sc0sc1: keep L2 clean) ----
    if (tid < 256) {
      int bl = tid >> 7;
      int b = r0 + bl;
      size_t ob = (size_t)b * (TT * FF) + (size_t)t * FF + fdot;
      cstoref(&out[ob], cc);
      cstoref(&out[BTF + ob], ch);
      cstoref(&out[2 * (size_t)BTF + ob], zh);
      cstoref(&out[3 * (size_t)BTF + ob], xh_r);
    }

    bar_wait(cntA, 32u * epA);

    // ---- phase2b: cc K-section (khalf0 waves, sec0 fragments, plain cc loads) ----
    if (khalf == 0) {
      const ushort_t* ccrow = ccbf + (size_t)arow * FF + quad * 8;
      bf16x8 AC[4];
#pragma unroll
      for (int kk = 0; kk < 4; ++kk) AC[kk] = *(const bf16x8*)(ccrow + kk * 32);
#pragma unroll
      for (int kk = 0; kk < 4; ++kk) {
#pragma unroll
        for (int nt = 0; nt < 4; ++nt) {
          acc[nt] = __builtin_amdgcn_mfma_f32_16x16x32_bf16(AC[kk], WFRAG(0, nt, kk), acc[nt], 0, 0, 0);
        }
      }
#pragma unroll
      for (int nt = 0; nt < 4; ++nt)
#pragma unroll
        for (int r = 0; r < 4; ++r)
          gates_lds[(mt * 16 + quad * 4 + r) * 68 + nt * 16 + lan] = acc[nt][r];
    }
    __syncthreads();

    // ---- LSTM epilogue: c in registers, write h (f32) + pre-decayed h (bf16), coherent ----
    {
      const float* g0 = &gates_lds[(size_t)b_l * 68 + jl0];
      const float* g1 = &gates_lds[(size_t)(64 + b_l) * 68 + jl0];
      float2 gI = make_float2(g0[0] + g1[0] + bias_lds[jl0],
                              g0[1] + g1[1] + bias_lds[jl0 + 1]);
      float2 gF = make_float2(g0[16] + g1[16] + bias_lds[16 + jl0],
                              g0[17] + g1[17] + bias_lds[16 + jl0 + 1]);
      float2 gG = make_float2(g0[32] + g1[32] + bias_lds[32 + jl0],
                              g0[33] + g1[33] + bias_lds[32 + jl0 + 1]);
      float2 gO = make_float2(g0[48] + g1[48] + bias_lds[48 + jl0],
                              g0[49] + g1[49] + bias_lds[48 + jl0 + 1]);
      c_r0 = fmaf(sigm(gF.x), c_r0, sigm(gI.x) * tanhf(gG.x));
      c_r1 = fmaf(sigm(gF.y), c_r1, sigm(gI.y) * tanhf(gG.y));
      float h0 = sigm(gO.x) * tanhf(c_r0);
      float h1 = sigm(gO.y) * tanhf(c_r1);
      float* hwN = hws + (size_t)((t + 1) & 1) * BH;
      ushort_t* hdN = hdws + (size_t)((t + 1) & 1) * BH;
      union { float2 f; unsigned long long q; } hu; hu.f = make_float2(h0, h1);
      cstore8(&hwN[(size_t)bglob * HH + j0], hu.q);
      float gHa = lo2f(gh2), gHb = hi2f(gh2);
      unsigned hp = ((unsigned)f2bf(h0 * gHa)) | (((unsigned)f2bf(h1 * gHb)) << 16);
      cstore4(&hdN[(size_t)bglob * HH + j0], hp);
    }

    // ---- barrier B arrive: h / hdec published ----
    bar_arrive(cntB); ++epB;
  }
#undef WFRAG
}

// ---------------- host ----------------
extern "C" void kernel_launch(void* const* d_in, const int* in_sizes, int n_in,
                              void* d_out, int out_size, void* d_ws, size_t ws_size,
                              hipStream_t stream) {
  (void)in_sizes; (void)n_in; (void)out_size; (void)ws_size;
  const float* x   = (const float*)d_in[0];
  const int*   mask= (const int*)d_in[1];
  const float* Wdh = (const float*)d_in[2];
  const float* bdh = (const float*)d_in[3];
  const float* Wdx = (const float*)d_in[4];
  const float* bdx = (const float*)d_in[5];
  const float* Wh  = (const float*)d_in[6];
  const float* bh  = (const float*)d_in[7];
  const float* Wf  = (const float*)d_in[8];
  const float* bfr = (const float*)d_in[9];
  const float* Wc  = (const float*)d_in[10];
  const float* bc  = (const float*)d_in[11];
  const float* Wih = (const float*)d_in[12];
  const float* Whh = (const float*)d_in[13];
  const float* bih = (const float*)d_in[14];
  const float* bhh = (const float*)d_in[15];
  float* out = (float*)d_out;
  char* ws = (char*)d_ws;

  hipLaunchKernelGGL(k_cvt,  dim3(1),   dim3(256), 0, stream, Wdx, ws);
  hipLaunchKernelGGL(k_prep, dim3(256), dim3(256), 0, stream, mask, ws);
  hipLaunchKernelGGL(k_gh,   dim3(768, 8), dim3(256), 0, stream, Wdh, bdh, ws);
  hipLaunchKernelGGL(k_al,   dim3(768, 2), dim3(256), 0, stream, Wc, bc, bdx, ws);

  hipFuncSetAttribute((const void*)k_main, hipFuncAttributeMaxDynamicSharedMemorySize, LDS_TOTAL);
  void* args[] = { (void*)&x, (void*)&mask, (void*)&Wh, (void*)&Wf, (void*)&bh, (void*)&bfr,
                   (void*)&Wih, (void*)&Whh, (void*)&bih, (void*)&bhh, (void*)&out, (void*)&ws };
  hipLaunchCooperativeKernel((const void*)k_main, dim3(256), dim3(512), args, LDS_TOTAL, stream);
}

// Round 10
// 1516.041 us; speedup vs baseline: 1.1955x; 1.1955x over previous
//
#include <hip/hip_runtime.h>
#include <cstdint>
#include <cstddef>

// ---------------- problem constants ----------------
#define BB 512
#define TT 96
#define FF 128
#define HH 512
#define BTF 6291456      // B*T*F
#define BH  262144       // B*H

typedef unsigned short ushort_t;
typedef __attribute__((ext_vector_type(8))) short bf16x8;
typedef __attribute__((ext_vector_type(4))) float f32x4;

// ---------------- ws layout (bytes) ----------------
static constexpr size_t OFF_FLAGS = 0;                        // 16 barrier counters, 128 B apart
static constexpr size_t OFF_WDXD  = 2048;                     // f32 [F] diag of Wdx
static constexpr size_t OFF_DELTA = 4096;                     // bf16 [T*B*F]
static constexpr size_t OFF_MBF   = OFF_DELTA + 12582912;     // bf16 [B*T*F]
static constexpr size_t OFF_ALPHA = OFF_MBF   + 12582912;     // bf16 [T*B*F]
static constexpr size_t OFF_GH    = OFF_ALPHA + 12582912;     // bf16 [T*B*H]
static constexpr size_t OFF_H     = OFF_GH    + 50331648;     // f32  [2][B*H] ping-pong
static constexpr size_t OFF_HDEC  = OFF_H     + 2097152;      // bf16 [2][B*H]
static constexpr size_t OFF_CCBF  = OFF_HDEC  + 1048576;      // bf16 [B*F]

// ---------------- k_main dynamic LDS layout (bytes) ----------------
// W_fr: fragment-packed gate weights. Slot ((sec*16 + nt*4 + kk)*64 + lane)*16B.
// Sections: 0=Wih cc (k0..128), 1=Wih m (k128..256), 2..5=Whh k(sec-2)*128.
// A wave's ds_read_b128 of one fragment covers 1024 contiguous bytes -> conflict-free.
static constexpr int LDS_W     = 0;          // 6*16*64*16 = 98304
static constexpr int LDS_GATES = 98304;      // 2 x 64 x 68 f32 = 34816
static constexpr int LDS_BIAS  = 133120;     // 64 f32 = 256
static constexpr int LDS_XPART = 133376;     // 16 x 128 f32 = 8192
static constexpr int LDS_XC    = 141568;     // 256 f32 = 1024
static constexpr int LDS_TOTAL = 142592;

// ---------------- helpers ----------------
__device__ __forceinline__ float bf2f(ushort_t u) {
  union { unsigned u; float f; } c; c.u = ((unsigned)u) << 16; return c.f;
}
__device__ __forceinline__ ushort_t f2bf(float f) {
  union { float f; unsigned u; } c; c.f = f;
  unsigned x = c.u;
  unsigned r = (x + 0x7FFFu + ((x >> 16) & 1u)) >> 16;
  return (ushort_t)r;
}
__device__ __forceinline__ float lo2f(unsigned p) {
  union { unsigned u; float f; } c; c.u = p << 16; return c.f;
}
__device__ __forceinline__ float hi2f(unsigned p) {
  union { unsigned u; float f; } c; c.u = p & 0xffff0000u; return c.f;
}
__device__ __forceinline__ float sigm(float v) { return 1.0f / (1.0f + __expf(-v)); }

// coherent (device-scope, per-access) helpers: compile to global_load/store sc0 sc1,
// NO wbl2/inv cache maintenance. (R9 lesson: acquire-inv destroys the read-only
// working set; per-access coherence is the fastest protocol on this chip.)
__device__ __forceinline__ bf16x8 cload16(const ushort_t* p) {
  union { unsigned long long q[2]; bf16x8 v; } u;
  unsigned long long* a = (unsigned long long*)p;
  u.q[0] = __hip_atomic_load(a,     __ATOMIC_RELAXED, __HIP_MEMORY_SCOPE_AGENT);
  u.q[1] = __hip_atomic_load(a + 1, __ATOMIC_RELAXED, __HIP_MEMORY_SCOPE_AGENT);
  return u.v;
}
__device__ __forceinline__ float cloadf(const float* p) {
  unsigned v = __hip_atomic_load((const unsigned*)p, __ATOMIC_RELAXED, __HIP_MEMORY_SCOPE_AGENT);
  union { unsigned u; float f; } c; c.u = v; return c.f;
}
__device__ __forceinline__ void cstore8(void* p, unsigned long long v) {
  __hip_atomic_store((unsigned long long*)p, v, __ATOMIC_RELAXED, __HIP_MEMORY_SCOPE_AGENT);
}
__device__ __forceinline__ void cstore4(void* p, unsigned v) {
  __hip_atomic_store((unsigned*)p, v, __ATOMIC_RELAXED, __HIP_MEMORY_SCOPE_AGENT);
}
__device__ __forceinline__ void cstore2(ushort_t* p, ushort_t v) {
  __hip_atomic_store(p, v, __ATOMIC_RELAXED, __HIP_MEMORY_SCOPE_AGENT);
}
__device__ __forceinline__ float rdlane_f(float v, int sl) {
  return __int_as_float(__builtin_amdgcn_readlane(__float_as_int(v), sl));
}

// ---------------- precompute: flag zero + Wdx diag ----------------
__global__ void k_cvt(const float* __restrict__ Wdx, char* __restrict__ ws) {
  int tid = threadIdx.x;
  unsigned* fl = (unsigned*)(ws + OFF_FLAGS);
  fl[tid] = 0; fl[256 + tid] = 0;
  float* wdxd = (float*)(ws + OFF_WDXD);
  if (tid < FF) wdxd[tid] = Wdx[tid * (FF + 1)];
}

// ---------------- precompute: delta recurrence + m bf16 ----------------
__global__ void k_prep(const int* __restrict__ mask, char* __restrict__ ws) {
  ushort_t* delta = (ushort_t*)(ws + OFF_DELTA);
  ushort_t* mbf   = (ushort_t*)(ws + OFF_MBF);
  int gtid = blockIdx.x * 256 + threadIdx.x;   // 65536 = B*F
  int b = gtid >> 7, f = gtid & 127;
  const int* mrow = mask + (size_t)b * (TT * FF) + f;
  float dprev = 0.0f;
  for (int t = 0; t < TT; ++t) {
    float d;
    if (t == 0) d = 0.0f;
    else {
      int mp = mrow[(t - 1) * FF];
      d = mp ? 1.0f : dprev + 1.0f;
    }
    dprev = d;
    delta[((size_t)t * BB + b) * FF + f] = f2bf(d);
    int mc = mrow[t * FF];
    mbf[(size_t)b * (TT * FF) + t * FF + f] = f2bf((float)mc);
  }
}

// ---------------- precompute: gamma_h = exp(-relu(delta @ Wdh^T + bdh)) ----------------
__global__ __launch_bounds__(256, 4) void k_gh(const float* __restrict__ Wdh,
                                               const float* __restrict__ bdh,
                                               char* __restrict__ ws) {
  __shared__ ushort_t A_lds[64 * 136];
  __shared__ ushort_t B_lds[64 * 136];
  const ushort_t* delta = (const ushort_t*)(ws + OFF_DELTA);
  ushort_t* gh = (ushort_t*)(ws + OFF_GH);
  int tid = threadIdx.x;
  int m0 = blockIdx.x * 64;
  int n0 = blockIdx.y * 64;
  for (int v = tid; v < 1024; v += 256) {
    int row = v >> 4, seg = v & 15;
    *(uint4*)&A_lds[row * 136 + seg * 8] =
        *(const uint4*)(delta + ((size_t)(m0 + row)) * FF + seg * 8);
  }
  for (int v = tid; v < 1024; v += 256) {
    int n = v >> 4, seg = v & 15;
    const float* src = Wdh + (size_t)(n0 + n) * FF + seg * 8;
    ushort_t tmp[8];
#pragma unroll
    for (int j = 0; j < 8; ++j) tmp[j] = f2bf(src[j]);
    *(uint4*)&B_lds[n * 136 + seg * 8] = *(const uint4*)tmp;
  }
  __syncthreads();
  int wave = tid >> 6, lane = tid & 63, quad = lane >> 4, lan = lane & 15;
  int mt = wave;
  f32x4 acc[4];
#pragma unroll
  for (int nt = 0; nt < 4; ++nt) acc[nt] = (f32x4){0.f, 0.f, 0.f, 0.f};
  const ushort_t* ab = &A_lds[(mt * 16 + lan) * 136 + quad * 8];
#pragma unroll
  for (int kk = 0; kk < 4; ++kk) {
    bf16x8 af = *(const bf16x8*)(ab + kk * 32);
#pragma unroll
    for (int nt = 0; nt < 4; ++nt) {
      bf16x8 bfv = *(const bf16x8*)(&B_lds[(nt * 16 + lan) * 136 + kk * 32 + quad * 8]);
      acc[nt] = __builtin_amdgcn_mfma_f32_16x16x32_bf16(af, bfv, acc[nt], 0, 0, 0);
    }
  }
#pragma unroll
  for (int nt = 0; nt < 4; ++nt) {
#pragma unroll
    for (int r = 0; r < 4; ++r) {
      int mg = m0 + mt * 16 + quad * 4 + r;
      int nc = n0 + nt * 16 + lan;
      float v = acc[nt][r] + bdh[nc];
      gh[(size_t)mg * HH + nc] = f2bf(__expf(-fmaxf(v, 0.0f)));
    }
  }
}

// ---------------- precompute: alpha = sigmoid([gamma_x, m] @ Wc^T + bc) ----------------
__global__ __launch_bounds__(256, 4) void k_al(const float* __restrict__ Wc,
                                               const float* __restrict__ bc,
                                               const float* __restrict__ bdx,
                                               char* __restrict__ ws) {
  __shared__ ushort_t A_lds[64 * 136];
  __shared__ ushort_t B_lds[64 * 136];
  const ushort_t* delta = (const ushort_t*)(ws + OFF_DELTA);
  const ushort_t* mbf   = (const ushort_t*)(ws + OFF_MBF);
  const float* wdxd     = (const float*)(ws + OFF_WDXD);
  ushort_t* alpha = (ushort_t*)(ws + OFF_ALPHA);
  int tid = threadIdx.x;
  int m0 = blockIdx.x * 64;
  int n0 = blockIdx.y * 64;
  int wave = tid >> 6, lane = tid & 63, quad = lane >> 4, lan = lane & 15;
  int mt = wave;
  f32x4 acc[4];
#pragma unroll
  for (int nt = 0; nt < 4; ++nt) acc[nt] = (f32x4){0.f, 0.f, 0.f, 0.f};
  for (int c = 0; c < 2; ++c) {
    __syncthreads();
    if (c == 0) {
      for (int v = tid; v < 1024; v += 256) {
        int row = v >> 4, seg = v & 15;
        int mg = m0 + row;
        ushort_t tmp[8];
#pragma unroll
        for (int j = 0; j < 8; ++j) {
          int k = seg * 8 + j;
          float d = bf2f(delta[(size_t)mg * FF + k]);
          float g = __expf(-fmaxf(fmaf(d, wdxd[k], bdx[k]), 0.0f));
          tmp[j] = f2bf(g);
        }
        *(uint4*)&A_lds[row * 136 + seg * 8] = *(const uint4*)tmp;
      }
    } else {
      for (int v = tid; v < 1024; v += 256) {
        int row = v >> 4, seg = v & 15;
        int mg = m0 + row;
        int t = mg >> 9, b = mg & 511;
        *(uint4*)&A_lds[row * 136 + seg * 8] =
            *(const uint4*)(mbf + ((size_t)b * TT + t) * FF + seg * 8);
      }
    }
    for (int v = tid; v < 1024; v += 256) {
      int n = v >> 4, seg = v & 15;
      const float* src = Wc + (size_t)(n0 + n) * 256 + c * 128 + seg * 8;
      ushort_t tmp[8];
#pragma unroll
      for (int j = 0; j < 8; ++j) tmp[j] = f2bf(src[j]);
      *(uint4*)&B_lds[n * 136 + seg * 8] = *(const uint4*)tmp;
    }
    __syncthreads();
    const ushort_t* ab = &A_lds[(mt * 16 + lan) * 136 + quad * 8];
#pragma unroll
    for (int kk = 0; kk < 4; ++kk) {
      bf16x8 af = *(const bf16x8*)(ab + kk * 32);
#pragma unroll
      for (int nt = 0; nt < 4; ++nt) {
        bf16x8 bfv = *(const bf16x8*)(&B_lds[(nt * 16 + lan) * 136 + kk * 32 + quad * 8]);
        acc[nt] = __builtin_amdgcn_mfma_f32_16x16x32_bf16(af, bfv, acc[nt], 0, 0, 0);
      }
    }
  }
#pragma unroll
  for (int nt = 0; nt < 4; ++nt) {
#pragma unroll
    for (int r = 0; r < 4; ++r) {
      int mg = m0 + mt * 16 + quad * 4 + r;
      int nc = n0 + nt * 16 + lan;
      float v = acc[nt][r] + bc[nc];
      alpha[(size_t)mg * FF + nc] = f2bf(sigm(v));
    }
  }
}

// ---------------- split group barrier: relaxed AGENT atomics (proven protocol) ----------
__device__ __forceinline__ void bar_arrive(unsigned* cnt) {
  __syncthreads();
  if (threadIdx.x == 0)
    __hip_atomic_fetch_add(cnt, 1u, __ATOMIC_RELAXED, __HIP_MEMORY_SCOPE_AGENT);
}
__device__ __forceinline__ void bar_wait(unsigned* cnt, unsigned target) {
  if (threadIdx.x == 0) {
    while (__hip_atomic_load(cnt, __ATOMIC_RELAXED, __HIP_MEMORY_SCOPE_AGENT) < target)
      __builtin_amdgcn_s_sleep(1);
  }
  __syncthreads();
}
// Per-wave wait (lane 0 polls; wave serializes on the masked loop). Used by khalf0
// waves for barrier A so their cc loads start the instant the count lands, without
// the full-WG __syncthreads release. Compiler fence stops load hoisting; HW ordering
// is safe (producers' sc0sc1 stores drained at vmcnt(0) before their counter add).
__device__ __forceinline__ void bar_wait_wave(unsigned* cnt, unsigned target, int lane) {
  if (lane == 0) {
    while (__hip_atomic_load(cnt, __ATOMIC_RELAXED, __HIP_MEMORY_SCOPE_AGENT) < target)
      __builtin_amdgcn_s_sleep(1);
  }
  asm volatile("" ::: "memory");
}

// ---------------- persistent cooperative kernel: 96-step recurrence ----------------
// grid 256 x 512 threads; dyn LDS 142592 B (1 WG/CU).
// Groups of 32 WGs by (wg & 7). Group g owns batch rows 64g..64g+63. Member m = wg>>3:
//   phase1: rows r0 = 64g + 2m (Wh/Wf in registers, readlane broadcast)
//   phase2: gate col-block ng = m, waves K-split (khalf).
//   Gate weights in FRAGMENT-PACKED LDS (W_fr): conflict-free ds_read_b128.
//   hdec LLC loads balanced 8/8 across wave classes (khalf0: c0+c1, khalf1: c2+c3);
//   khalf0 MFMA sections: m,c0,c1 (+cc in phase2b); khalf1: c2,c3 (publishes early).
// Cross-WG arrays (hws, hdws, ccbf) are accessed ONLY via relaxed agent atomics.
__global__ __launch_bounds__(512, 2) void k_main(
    const float* __restrict__ x, const int* __restrict__ mask,
    const float* __restrict__ Wh, const float* __restrict__ Wf,
    const float* __restrict__ bh, const float* __restrict__ bfr,
    const float* __restrict__ Wih, const float* __restrict__ Whh,
    const float* __restrict__ bih, const float* __restrict__ bhh,
    float* __restrict__ out, char* __restrict__ ws) {
  extern __shared__ char smem[];
  ushort_t* W_fr     = (ushort_t*)(smem + LDS_W);
  float* gates_lds   = (float*)(smem + LDS_GATES);
  float* bias_lds    = (float*)(smem + LDS_BIAS);
  float* xh_part     = (float*)(smem + LDS_XPART);
  float* xc_s        = (float*)(smem + LDS_XC);

  unsigned* cnts = (unsigned*)(ws + OFF_FLAGS);
  const ushort_t* alpha = (const ushort_t*)(ws + OFF_ALPHA);
  const ushort_t* gh    = (const ushort_t*)(ws + OFF_GH);
  const ushort_t* mbf   = (const ushort_t*)(ws + OFF_MBF);
  float*    hws  = (float*)(ws + OFF_H);
  ushort_t* hdws = (ushort_t*)(ws + OFF_HDEC);
  ushort_t* ccbf = (ushort_t*)(ws + OFF_CCBF);

  const int tid  = threadIdx.x;
  const int wg   = blockIdx.x;
  const int g    = wg & 7;          // group (XCD-locality heuristic only)
  const int mwg  = wg >> 3;         // member 0..31
  const int ng   = mwg;             // gate col-block
  const int wave = tid >> 6, lane = tid & 63, quad = lane >> 4, lan = lane & 15;
  const int mt = wave & 3, khalf = wave >> 2;
  const int r0 = g * 64 + mwg * 2;  // phase1 rows
  const int arow = g * 64 + mt * 16 + lan;   // phase2 A-fragment batch row

  unsigned* cntA = cnts + (g * 2 + 0) * 32;
  unsigned* cntB = cnts + (g * 2 + 1) * 32;

  // ---- init: gate-weight slice -> fragment-packed LDS (bf16) ----
  for (int q = tid; q < 6144; q += 512) {
    int sec = q >> 10, rem = q & 1023;
    int f = rem >> 6, lw = rem & 63;
    int nt = f >> 2, kk = f & 3;
    int lan_ = lw & 15, quad_ = lw >> 4;
    int r = nt * 512 + ng * 16 + lan_;
    const float* src = (sec < 2)
        ? (Wih + (size_t)r * 256 + sec * 128 + kk * 32 + quad_ * 8)
        : (Whh + (size_t)r * 512 + (sec - 2) * 128 + kk * 32 + quad_ * 8);
    float4 v0 = *(const float4*)src;
    float4 v1 = *(const float4*)(src + 4);
    ushort_t t8[8] = { f2bf(v0.x), f2bf(v0.y), f2bf(v0.z), f2bf(v0.w),
                       f2bf(v1.x), f2bf(v1.y), f2bf(v1.z), f2bf(v1.w) };
    *(uint4*)&W_fr[q * 8] = *(const uint4*)t8;
  }
  if (tid < 64) {
    int r = (tid >> 4) * 512 + ng * 16 + (tid & 15);
    bias_lds[tid] = bih[r] + bhh[r];
  }

#define WFRAG(sec, nt, kk) (*(const bf16x8*)&W_fr[((((sec) * 16 + (nt) * 4 + (kk)) * 64 + lane)) * 8])

  // ---- init: Wh / Wf slices -> registers ----
  unsigned wh_p[64];
  {
    const float* s0 = Wh + (size_t)lane * HH + 64 * wave;
    const float* s1 = Wh + (size_t)(lane + 64) * HH + 64 * wave;
#pragma unroll
    for (int i4 = 0; i4 < 16; ++i4) {
      float4 a = *(const float4*)(s0 + i4 * 4);
      float4 b = *(const float4*)(s1 + i4 * 4);
      wh_p[i4 * 4 + 0] = ((unsigned)f2bf(a.x)) | (((unsigned)f2bf(b.x)) << 16);
      wh_p[i4 * 4 + 1] = ((unsigned)f2bf(a.y)) | (((unsigned)f2bf(b.y)) << 16);
      wh_p[i4 * 4 + 2] = ((unsigned)f2bf(a.z)) | (((unsigned)f2bf(b.z)) << 16);
      wh_p[i4 * 4 + 3] = ((unsigned)f2bf(a.w)) | (((unsigned)f2bf(b.w)) << 16);
    }
  }
  unsigned wf_p[16];
  {
    const float* s0 = Wf + (size_t)lane * FF + 16 * wave;
    const float* s1 = Wf + (size_t)(lane + 64) * FF + 16 * wave;
#pragma unroll
    for (int i4 = 0; i4 < 4; ++i4) {
      float4 a = *(const float4*)(s0 + i4 * 4);
      float4 b = *(const float4*)(s1 + i4 * 4);
      wf_p[i4 * 4 + 0] = ((unsigned)f2bf(a.x)) | (((unsigned)f2bf(b.x)) << 16);
      wf_p[i4 * 4 + 1] = ((unsigned)f2bf(a.y)) | (((unsigned)f2bf(b.y)) << 16);
      wf_p[i4 * 4 + 2] = ((unsigned)f2bf(a.z)) | (((unsigned)f2bf(b.z)) << 16);
      wf_p[i4 * 4 + 3] = ((unsigned)f2bf(a.w)) | (((unsigned)f2bf(b.w)) << 16);
    }
  }
  const int fdot = tid & 127;        // scalar-chain output index (tid<256 lanes)
  float bh_r = 0.f, bfr_r = 0.f, wfd_r = 0.f;
  if (tid < 256) {
    bh_r  = bh[fdot];
    bfr_r = bfr[fdot];
    wfd_r = bf2f(f2bf(Wf[(size_t)fdot * FF + fdot]));  // matches bf16 dot term exactly
  }

  // ---- init: zero owned state slices (buffer 0, coherent stores) ----
  const int b_l = tid >> 3, jl0 = 2 * (tid & 7);     // epilogue mapping
  const int bglob = g * 64 + b_l, j0 = ng * 16 + jl0;
  cstore8(&hws[(size_t)bglob * HH + j0], 0ull);
  cstore4(&hdws[(size_t)bglob * HH + j0], 0u);
  float c_r0 = 0.f, c_r1 = 0.f;

  unsigned epA = 0, epB = 1;
  bar_arrive(cntB);

  for (int t = 0; t < TT; ++t) {
    // ---- prefetch step-indexed inputs (read-only, normal cached loads) ----
    float xv = 0.f, mv = 0.f, al = 0.f;
    if (tid < 256) {
      int bl = tid >> 7;
      int b = r0 + bl;
      size_t gix = (size_t)b * (TT * FF) + (size_t)t * FF + fdot;
      xv = x[gix];
      mv = (float)mask[gix];
      al = bf2f(alpha[((size_t)t * BB + b) * FF + fdot]);
    }
    unsigned gh2 = 0;
    if (t < TT - 1)
      gh2 = *(const unsigned*)&gh[((size_t)(t + 1) * BB + bglob) * HH + j0];
    bf16x8 A0[4], A1[4], A2[4];
    if (khalf == 0) {                                   // m-chunk: precomputed, cached
      const ushort_t* mrow = mbf + ((size_t)arow * TT + t) * FF + quad * 8;
#pragma unroll
      for (int kk = 0; kk < 4; ++kk) A0[kk] = *(const bf16x8*)(mrow + kk * 32);
    }

    // ---- wait for h/hdec of this step ----
    bar_wait(cntB, 32u * epB);

    // ---- coherent loads: h one element/lane + hdec A-fragments (8/8 balanced) ----
    const float* hbuf = hws + (size_t)(t & 1) * BH;
    float h0r = cloadf(hbuf + (size_t)r0 * HH + 64 * wave + lane);
    float h1r = cloadf(hbuf + (size_t)(r0 + 1) * HH + 64 * wave + lane);
    {
      const ushort_t* hdec = hdws + (size_t)(t & 1) * BH;
      const ushort_t* hrow = hdec + (size_t)arow * HH + quad * 8;
      if (khalf == 0) {
#pragma unroll
        for (int kk = 0; kk < 4; ++kk) A1[kk] = cload16(hrow + kk * 32);        // c0
#pragma unroll
        for (int kk = 0; kk < 4; ++kk) A2[kk] = cload16(hrow + 128 + kk * 32);  // c1
      } else {
#pragma unroll
        for (int kk = 0; kk < 4; ++kk) A0[kk] = cload16(hrow + 256 + kk * 32);  // c2
#pragma unroll
        for (int kk = 0; kk < 4; ++kk) A1[kk] = cload16(hrow + 384 + kk * 32);  // c3
      }
    }

    // ---- phase2a MFMA (K-sections not depending on cc) ----
    f32x4 acc[4];
#pragma unroll
    for (int nt = 0; nt < 4; ++nt) acc[nt] = (f32x4){0.f, 0.f, 0.f, 0.f};
    if (khalf == 0) {
      // sections: m (sec1), hdec c0 (sec2), hdec c1 (sec3)
#pragma unroll
      for (int kk = 0; kk < 4; ++kk)
#pragma unroll
        for (int nt = 0; nt < 4; ++nt)
          acc[nt] = __builtin_amdgcn_mfma_f32_16x16x32_bf16(A0[kk], WFRAG(1, nt, kk), acc[nt], 0, 0, 0);
#pragma unroll
      for (int kk = 0; kk < 4; ++kk)
#pragma unroll
        for (int nt = 0; nt < 4; ++nt)
          acc[nt] = __builtin_amdgcn_mfma_f32_16x16x32_bf16(A1[kk], WFRAG(2, nt, kk), acc[nt], 0, 0, 0);
#pragma unroll
      for (int kk = 0; kk < 4; ++kk)
#pragma unroll
        for (int nt = 0; nt < 4; ++nt)
          acc[nt] = __builtin_amdgcn_mfma_f32_16x16x32_bf16(A2[kk], WFRAG(3, nt, kk), acc[nt], 0, 0, 0);
    } else {
      // sections: hdec c2 (sec4), hdec c3 (sec5)
#pragma unroll
      for (int kk = 0; kk < 4; ++kk)
#pragma unroll
        for (int nt = 0; nt < 4; ++nt)
          acc[nt] = __builtin_amdgcn_mfma_f32_16x16x32_bf16(A0[kk], WFRAG(4, nt, kk), acc[nt], 0, 0, 0);
#pragma unroll
      for (int kk = 0; kk < 4; ++kk)
#pragma unroll
        for (int nt = 0; nt < 4; ++nt)
          acc[nt] = __builtin_amdgcn_mfma_f32_16x16x32_bf16(A1[kk], WFRAG(5, nt, kk), acc[nt], 0, 0, 0);
      // khalf1 waves are done: publish partial gates now
#pragma unroll
      for (int nt = 0; nt < 4; ++nt)
#pragma unroll
        for (int r = 0; r < 4; ++r)
          gates_lds[(64 + mt * 16 + quad * 4 + r) * 68 + nt * 16 + lan] = acc[nt][r];
    }

    // ---- phase1: xh dot, VALU readlane broadcast ----
    {
      float a00 = 0.f, a01 = 0.f, a10 = 0.f, a11 = 0.f;
#pragma unroll
      for (int k = 0; k < 64; ++k) {
        float hk0 = rdlane_f(h0r, k);
        float hk1 = rdlane_f(h1r, k);
        unsigned wp = wh_p[k];
        float w0 = lo2f(wp), w1 = hi2f(wp);
        a00 = fmaf(w0, hk0, a00);
        a10 = fmaf(w1, hk0, a10);
        a01 = fmaf(w0, hk1, a01);
        a11 = fmaf(w1, hk1, a11);
      }
      xh_part[(wave * 2 + 0) * 128 + lane]      = a00;
      xh_part[(wave * 2 + 0) * 128 + 64 + lane] = a10;
      xh_part[(wave * 2 + 1) * 128 + lane]      = a01;
      xh_part[(wave * 2 + 1) * 128 + 64 + lane] = a11;
    }
    __syncthreads();

    float xh_r = 0.f;
    if (tid < 256) {
      int bl = tid >> 7;
      float s = bh_r;
#pragma unroll
      for (int w2 = 0; w2 < 8; ++w2) s += xh_part[(w2 * 2 + bl) * 128 + fdot];
      xh_r = s;
      float xcv = fmaf(1.0f - mv, xh_r, mv * xv);
      xc_s[bl * 128 + fdot] = xcv;
    }
    __syncthreads();

    // ---- z_h dot (same mapping, K-slice of 16 per wave) ----
    {
      float z00 = 0.f, z01 = 0.f, z10 = 0.f, z11 = 0.f;
      float x0 = xc_s[16 * wave + (lane & 15)];
      float x1 = xc_s[128 + 16 * wave + (lane & 15)];
#pragma unroll
      for (int k = 0; k < 16; ++k) {
        float xk0 = rdlane_f(x0, k);
        float xk1 = rdlane_f(x1, k);
        unsigned wp = wf_p[k];
        float w0 = lo2f(wp), w1 = hi2f(wp);
        z00 = fmaf(w0, xk0, z00);
        z10 = fmaf(w1, xk0, z10);
        z01 = fmaf(w0, xk1, z01);
        z11 = fmaf(w1, xk1, z11);
      }
      xh_part[(wave * 2 + 0) * 128 + lane]      = z00;
      xh_part[(wave * 2 + 0) * 128 + 64 + lane] = z10;
      xh_part[(wave * 2 + 1) * 128 + lane]      = z01;
      xh_part[(wave * 2 + 1) * 128 + 64 + lane] = z11;
    }
    __syncthreads();

    float zh = 0.f, ch = 0.f, cc = 0.f;
    if (tid < 256) {
      int bl = tid >> 7;
      int b = r0 + bl;
      float xcv = xc_s[bl * 128 + fdot];
      float s = bfr_r - xcv * wfd_r;
#pragma unroll
      for (int w2 = 0; w2 < 8; ++w2) s += xh_part[(w2 * 2 + bl) * 128 + fdot];
      zh = s;
      ch = fmaf(al, zh, (1.0f - al) * xh_r);
      cc = fmaf(1.0f - mv, ch, mv * xv);
      cstore2(&ccbf[b * FF + fdot], f2bf(cc));          // coherent: cross-WG consumed
    }

    // ---- barrier A arrive: cc published ----
    bar_arrive(cntA); ++epA;

    // ---- out[] stores overlap barrier-A latency (host-only consumers) ----
    if (tid < 256) {
      int bl = tid >> 7;
      int b = r0 + bl;
      size_t ob = (size_t)b * (TT * FF) + (size_t)t * FF + fdot;
      out[ob] = cc;
      out[BTF + ob] = ch;
      out[2 * (size_t)BTF + ob] = zh;
      out[3 * (size_t)BTF + ob] = xh_r;
    }

    // ---- phase2b: khalf0 waves self-release on barrier A (per-wave poll) ----
    if (khalf == 0) {
      bar_wait_wave(cntA, 32u * epA, lane);
      const ushort_t* ccrow = ccbf + (size_t)arow * FF + quad * 8;
      bf16x8 AC[4];
#pragma unroll
      for (int kk = 0; kk < 4; ++kk) AC[kk] = cload16(ccrow + kk * 32);
#pragma unroll
      for (int kk = 0; kk < 4; ++kk) {
#pragma unroll
        for (int nt = 0; nt < 4; ++nt) {
          acc[nt] = __builtin_amdgcn_mfma_f32_16x16x32_bf16(AC[kk], WFRAG(0, nt, kk), acc[nt], 0, 0, 0);
        }
      }
#pragma unroll
      for (int nt = 0; nt < 4; ++nt)
#pragma unroll
        for (int r = 0; r < 4; ++r)
          gates_lds[(mt * 16 + quad * 4 + r) * 68 + nt * 16 + lan] = acc[nt][r];
    }
    __syncthreads();

    // ---- LSTM epilogue: c in registers, write h (f32) + pre-decayed h (bf16), coherent ----
    {
      const float* g0 = &gates_lds[(size_t)b_l * 68 + jl0];
      const float* g1 = &gates_lds[(size_t)(64 + b_l) * 68 + jl0];
      float2 gI = make_float2(g0[0] + g1[0] + bias_lds[jl0],
                              g0[1] + g1[1] + bias_lds[jl0 + 1]);
      float2 gF = make_float2(g0[16] + g1[16] + bias_lds[16 + jl0],
                              g0[17] + g1[17] + bias_lds[16 + jl0 + 1]);
      float2 gG = make_float2(g0[32] + g1[32] + bias_lds[32 + jl0],
                              g0[33] + g1[33] + bias_lds[32 + jl0 + 1]);
      float2 gO = make_float2(g0[48] + g1[48] + bias_lds[48 + jl0],
                              g0[49] + g1[49] + bias_lds[48 + jl0 + 1]);
      c_r0 = fmaf(sigm(gF.x), c_r0, sigm(gI.x) * tanhf(gG.x));
      c_r1 = fmaf(sigm(gF.y), c_r1, sigm(gI.y) * tanhf(gG.y));
      float h0 = sigm(gO.x) * tanhf(c_r0);
      float h1 = sigm(gO.y) * tanhf(c_r1);
      float* hwN = hws + (size_t)((t + 1) & 1) * BH;
      ushort_t* hdN = hdws + (size_t)((t + 1) & 1) * BH;
      union { float2 f; unsigned long long q; } hu; hu.f = make_float2(h0, h1);
      cstore8(&hwN[(size_t)bglob * HH + j0], hu.q);
      float gHa = lo2f(gh2), gHb = hi2f(gh2);
      unsigned hp = ((unsigned)f2bf(h0 * gHa)) | (((unsigned)f2bf(h1 * gHb)) << 16);
      cstore4(&hdN[(size_t)bglob * HH + j0], hp);
    }

    // ---- barrier B arrive: h / hdec published ----
    bar_arrive(cntB); ++epB;
  }
#undef WFRAG
}

// ---------------- host ----------------
extern "C" void kernel_launch(void* const* d_in, const int* in_sizes, int n_in,
                              void* d_out, int out_size, void* d_ws, size_t ws_size,
                              hipStream_t stream) {
  (void)in_sizes; (void)n_in; (void)out_size; (void)ws_size;
  const float* x   = (const float*)d_in[0];
  const int*   mask= (const int*)d_in[1];
  const float* Wdh = (const float*)d_in[2];
  const float* bdh = (const float*)d_in[3];
  const float* Wdx = (const float*)d_in[4];
  const float* bdx = (const float*)d_in[5];
  const float* Wh  = (const float*)d_in[6];
  const float* bh  = (const float*)d_in[7];
  const float* Wf  = (const float*)d_in[8];
  const float* bfr = (const float*)d_in[9];
  const float* Wc  = (const float*)d_in[10];
  const float* bc  = (const float*)d_in[11];
  const float* Wih = (const float*)d_in[12];
  const float* Whh = (const float*)d_in[13];
  const float* bih = (const float*)d_in[14];
  const float* bhh = (const float*)d_in[15];
  float* out = (float*)d_out;
  char* ws = (char*)d_ws;

  hipLaunchKernelGGL(k_cvt,  dim3(1),   dim3(256), 0, stream, Wdx, ws);
  hipLaunchKernelGGL(k_prep, dim3(256), dim3(256), 0, stream, mask, ws);
  hipLaunchKernelGGL(k_gh,   dim3(768, 8), dim3(256), 0, stream, Wdh, bdh, ws);
  hipLaunchKernelGGL(k_al,   dim3(768, 2), dim3(256), 0, stream, Wc, bc, bdx, ws);

  hipFuncSetAttribute((const void*)k_main, hipFuncAttributeMaxDynamicSharedMemorySize, LDS_TOTAL);
  void* args[] = { (void*)&x, (void*)&mask, (void*)&Wh, (void*)&Wf, (void*)&bh, (void*)&bfr,
                   (void*)&Wih, (void*)&Whh, (void*)&bih, (void*)&bhh, (void*)&out, (void*)&ws };
  hipLaunchCooperativeKernel((const void*)k_main, dim3(256), dim3(512), args, LDS_TOTAL, stream);
}

// Round 11
// 1356.035 us; speedup vs baseline: 1.3366x; 1.1180x over previous
//
#include <hip/hip_runtime.h>
#include <cstdint>
#include <cstddef>

// ---------------- problem constants ----------------
#define BB 512
#define TT 96
#define FF 128
#define HH 512
#define BTF 6291456      // B*T*F
#define BH  262144       // B*H

typedef unsigned short ushort_t;
typedef __attribute__((ext_vector_type(8))) short bf16x8;
typedef __attribute__((ext_vector_type(4))) float f32x4;

// ---------------- ws layout (bytes) ----------------
static constexpr size_t OFF_FLAGS = 0;                        // 16 barrier counters, 128 B apart
static constexpr size_t OFF_WDXD  = 2048;                     // f32 [F] diag of Wdx
static constexpr size_t OFF_DELTA = 4096;                     // bf16 [T*B*F]
static constexpr size_t OFF_MBF   = OFF_DELTA + 12582912;     // bf16 [B*T*F]
static constexpr size_t OFF_ALPHA = OFF_MBF   + 12582912;     // bf16 [T*B*F]
static constexpr size_t OFF_GH    = OFF_ALPHA + 12582912;     // bf16 [T*B*H]
static constexpr size_t OFF_H     = OFF_GH    + 50331648;     // f32  [2][B*H] ping-pong
static constexpr size_t OFF_HDEC  = OFF_H     + 2097152;      // bf16 [2][B*H]
static constexpr size_t OFF_CCBF  = OFF_HDEC  + 1048576;      // bf16 [B*F]

// ---------------- k_main dynamic LDS layout (bytes) ----------------
static constexpr int LDS_W     = 0;          // 6*16*64*16 = 98304 (fragment-packed, conflict-free)
static constexpr int LDS_GATES = 98304;      // 2 x 64 x 68 f32 = 34816
static constexpr int LDS_BIAS  = 133120;     // 64 f32 = 256
static constexpr int LDS_XPART = 133376;     // 16 x 128 f32 = 8192
static constexpr int LDS_XC    = 141568;     // 256 f32 = 1024
static constexpr int LDS_MISC  = 142592;     // slot broadcast (16 B)
static constexpr int LDS_TOTAL = 142608;

// ---------------- helpers ----------------
__device__ __forceinline__ float bf2f(ushort_t u) {
  union { unsigned u; float f; } c; c.u = ((unsigned)u) << 16; return c.f;
}
__device__ __forceinline__ ushort_t f2bf(float f) {
  union { float f; unsigned u; } c; c.f = f;
  unsigned x = c.u;
  unsigned r = (x + 0x7FFFu + ((x >> 16) & 1u)) >> 16;
  return (ushort_t)r;
}
__device__ __forceinline__ float lo2f(unsigned p) {
  union { unsigned u; float f; } c; c.u = p << 16; return c.f;
}
__device__ __forceinline__ float hi2f(unsigned p) {
  union { unsigned u; float f; } c; c.u = p & 0xffff0000u; return c.f;
}
__device__ __forceinline__ float sigm(float v) { return 1.0f / (1.0f + __expf(-v)); }

// ---- XCD-local exchange primitives ----
// Group == physical XCD (1 WG/CU * 256 WGs -> exactly 32 WGs per XCD; grouping by
// HW_REG_XCC_ID). Exchange STORES are plain (write-through -> dirty in the XCD's L2);
// exchange LOADS are sc0-only (bypass L1, HIT the shared XCD L2 -> ~200cy vs ~700cy
// LLC). The group barrier stays LLC-scope (proven protocol) and orders the exchange:
// producer's plain stores drain at __syncthreads' vmcnt(0) BEFORE its LLC arrive.
// Rule #18: each asm-load batch is followed by s_waitcnt vmcnt(0) + sched_barrier.
__device__ __forceinline__ bf16x8 ld16_l2(const ushort_t* p) {   // issue only, no wait
  bf16x8 r;
  asm volatile("global_load_dwordx4 %0, %1, off sc0" : "=v"(r) : "v"(p));
  return r;
}
__device__ __forceinline__ float ldf_l2(const float* p) {        // issue only, no wait
  float r;
  asm volatile("global_load_dword %0, %1, off sc0" : "=v"(r) : "v"(p));
  return r;
}
__device__ __forceinline__ void waitvm0() {
  asm volatile("s_waitcnt vmcnt(0)" ::: "memory");
  __builtin_amdgcn_sched_barrier(0);
}
__device__ __forceinline__ float rdlane_f(float v, int sl) {
  return __int_as_float(__builtin_amdgcn_readlane(__float_as_int(v), sl));
}

// ---------------- precompute: flag zero + Wdx diag ----------------
__global__ void k_cvt(const float* __restrict__ Wdx, char* __restrict__ ws) {
  int tid = threadIdx.x;
  unsigned* fl = (unsigned*)(ws + OFF_FLAGS);
  fl[tid] = 0; fl[256 + tid] = 0;       // zeroes barrier counters AND slot counters
  float* wdxd = (float*)(ws + OFF_WDXD);
  if (tid < FF) wdxd[tid] = Wdx[tid * (FF + 1)];
}

// ---------------- precompute: delta recurrence + m bf16 ----------------
__global__ void k_prep(const int* __restrict__ mask, char* __restrict__ ws) {
  ushort_t* delta = (ushort_t*)(ws + OFF_DELTA);
  ushort_t* mbf   = (ushort_t*)(ws + OFF_MBF);
  int gtid = blockIdx.x * 256 + threadIdx.x;   // 65536 = B*F
  int b = gtid >> 7, f = gtid & 127;
  const int* mrow = mask + (size_t)b * (TT * FF) + f;
  float dprev = 0.0f;
  for (int t = 0; t < TT; ++t) {
    float d;
    if (t == 0) d = 0.0f;
    else {
      int mp = mrow[(t - 1) * FF];
      d = mp ? 1.0f : dprev + 1.0f;
    }
    dprev = d;
    delta[((size_t)t * BB + b) * FF + f] = f2bf(d);
    int mc = mrow[t * FF];
    mbf[(size_t)b * (TT * FF) + t * FF + f] = f2bf((float)mc);
  }
}

// ---------------- precompute: gamma_h = exp(-relu(delta @ Wdh^T + bdh)) ----------------
__global__ __launch_bounds__(256, 4) void k_gh(const float* __restrict__ Wdh,
                                               const float* __restrict__ bdh,
                                               char* __restrict__ ws) {
  __shared__ ushort_t A_lds[64 * 136];
  __shared__ ushort_t B_lds[64 * 136];
  const ushort_t* delta = (const ushort_t*)(ws + OFF_DELTA);
  ushort_t* gh = (ushort_t*)(ws + OFF_GH);
  int tid = threadIdx.x;
  int m0 = blockIdx.x * 64;
  int n0 = blockIdx.y * 64;
  for (int v = tid; v < 1024; v += 256) {
    int row = v >> 4, seg = v & 15;
    *(uint4*)&A_lds[row * 136 + seg * 8] =
        *(const uint4*)(delta + ((size_t)(m0 + row)) * FF + seg * 8);
  }
  for (int v = tid; v < 1024; v += 256) {
    int n = v >> 4, seg = v & 15;
    const float* src = Wdh + (size_t)(n0 + n) * FF + seg * 8;
    ushort_t tmp[8];
#pragma unroll
    for (int j = 0; j < 8; ++j) tmp[j] = f2bf(src[j]);
    *(uint4*)&B_lds[n * 136 + seg * 8] = *(const uint4*)tmp;
  }
  __syncthreads();
  int wave = tid >> 6, lane = tid & 63, quad = lane >> 4, lan = lane & 15;
  int mt = wave;
  f32x4 acc[4];
#pragma unroll
  for (int nt = 0; nt < 4; ++nt) acc[nt] = (f32x4){0.f, 0.f, 0.f, 0.f};
  const ushort_t* ab = &A_lds[(mt * 16 + lan) * 136 + quad * 8];
#pragma unroll
  for (int kk = 0; kk < 4; ++kk) {
    bf16x8 af = *(const bf16x8*)(ab + kk * 32);
#pragma unroll
    for (int nt = 0; nt < 4; ++nt) {
      bf16x8 bfv = *(const bf16x8*)(&B_lds[(nt * 16 + lan) * 136 + kk * 32 + quad * 8]);
      acc[nt] = __builtin_amdgcn_mfma_f32_16x16x32_bf16(af, bfv, acc[nt], 0, 0, 0);
    }
  }
#pragma unroll
  for (int nt = 0; nt < 4; ++nt) {
#pragma unroll
    for (int r = 0; r < 4; ++r) {
      int mg = m0 + mt * 16 + quad * 4 + r;
      int nc = n0 + nt * 16 + lan;
      float v = acc[nt][r] + bdh[nc];
      gh[(size_t)mg * HH + nc] = f2bf(__expf(-fmaxf(v, 0.0f)));
    }
  }
}

// ---------------- precompute: alpha = sigmoid([gamma_x, m] @ Wc^T + bc) ----------------
__global__ __launch_bounds__(256, 4) void k_al(const float* __restrict__ Wc,
                                               const float* __restrict__ bc,
                                               const float* __restrict__ bdx,
                                               char* __restrict__ ws) {
  __shared__ ushort_t A_lds[64 * 136];
  __shared__ ushort_t B_lds[64 * 136];
  const ushort_t* delta = (const ushort_t*)(ws + OFF_DELTA);
  const ushort_t* mbf   = (const ushort_t*)(ws + OFF_MBF);
  const float* wdxd     = (const float*)(ws + OFF_WDXD);
  ushort_t* alpha = (ushort_t*)(ws + OFF_ALPHA);
  int tid = threadIdx.x;
  int m0 = blockIdx.x * 64;
  int n0 = blockIdx.y * 64;
  int wave = tid >> 6, lane = tid & 63, quad = lane >> 4, lan = lane & 15;
  int mt = wave;
  f32x4 acc[4];
#pragma unroll
  for (int nt = 0; nt < 4; ++nt) acc[nt] = (f32x4){0.f, 0.f, 0.f, 0.f};
  for (int c = 0; c < 2; ++c) {
    __syncthreads();
    if (c == 0) {
      for (int v = tid; v < 1024; v += 256) {
        int row = v >> 4, seg = v & 15;
        int mg = m0 + row;
        ushort_t tmp[8];
#pragma unroll
        for (int j = 0; j < 8; ++j) {
          int k = seg * 8 + j;
          float d = bf2f(delta[(size_t)mg * FF + k]);
          float g = __expf(-fmaxf(fmaf(d, wdxd[k], bdx[k]), 0.0f));
          tmp[j] = f2bf(g);
        }
        *(uint4*)&A_lds[row * 136 + seg * 8] = *(const uint4*)tmp;
      }
    } else {
      for (int v = tid; v < 1024; v += 256) {
        int row = v >> 4, seg = v & 15;
        int mg = m0 + row;
        int t = mg >> 9, b = mg & 511;
        *(uint4*)&A_lds[row * 136 + seg * 8] =
            *(const uint4*)(mbf + ((size_t)b * TT + t) * FF + seg * 8);
      }
    }
    for (int v = tid; v < 1024; v += 256) {
      int n = v >> 4, seg = v & 15;
      const float* src = Wc + (size_t)(n0 + n) * 256 + c * 128 + seg * 8;
      ushort_t tmp[8];
#pragma unroll
      for (int j = 0; j < 8; ++j) tmp[j] = f2bf(src[j]);
      *(uint4*)&B_lds[n * 136 + seg * 8] = *(const uint4*)tmp;
    }
    __syncthreads();
    const ushort_t* ab = &A_lds[(mt * 16 + lan) * 136 + quad * 8];
#pragma unroll
    for (int kk = 0; kk < 4; ++kk) {
      bf16x8 af = *(const bf16x8*)(ab + kk * 32);
#pragma unroll
      for (int nt = 0; nt < 4; ++nt) {
        bf16x8 bfv = *(const bf16x8*)(&B_lds[(nt * 16 + lan) * 136 + kk * 32 + quad * 8]);
        acc[nt] = __builtin_amdgcn_mfma_f32_16x16x32_bf16(af, bfv, acc[nt], 0, 0, 0);
      }
    }
  }
#pragma unroll
  for (int nt = 0; nt < 4; ++nt) {
#pragma unroll
    for (int r = 0; r < 4; ++r) {
      int mg = m0 + mt * 16 + quad * 4 + r;
      int nc = n0 + nt * 16 + lan;
      float v = acc[nt][r] + bc[nc];
      alpha[(size_t)mg * FF + nc] = f2bf(sigm(v));
    }
  }
}

// ---------------- split group barrier: relaxed AGENT atomics (proven LLC protocol) ----
__device__ __forceinline__ void bar_arrive(unsigned* cnt) {
  __syncthreads();
  if (threadIdx.x == 0)
    __hip_atomic_fetch_add(cnt, 1u, __ATOMIC_RELAXED, __HIP_MEMORY_SCOPE_AGENT);
}
__device__ __forceinline__ void bar_wait(unsigned* cnt, unsigned target) {
  if (threadIdx.x == 0) {
    while (__hip_atomic_load(cnt, __ATOMIC_RELAXED, __HIP_MEMORY_SCOPE_AGENT) < target)
      __builtin_amdgcn_s_sleep(1);
  }
  __syncthreads();
}
// Per-wave wait (lane 0 polls; wave serializes on the masked loop). Compiler fence
// stops hoisting; HW: loads after the poll are control-dependent on its result.
__device__ __forceinline__ void bar_wait_wave(unsigned* cnt, unsigned target, int lane) {
  if (lane == 0) {
    while (__hip_atomic_load(cnt, __ATOMIC_RELAXED, __HIP_MEMORY_SCOPE_AGENT) < target)
      __builtin_amdgcn_s_sleep(1);
  }
  asm volatile("" ::: "memory");
}

// ---------------- persistent cooperative kernel: 96-step recurrence ----------------
// grid 256 x 512 threads; dyn LDS 142608 B -> exactly 1 WG/CU -> exactly 32 WGs/XCD.
// Group g == physical XCD (HW_REG_XCC_ID); member = per-XCD slot (one-time LLC atomic).
// Exchange arrays (hws, hdws, ccbf): PLAIN stores (dirty in the XCD's L2) + sc0 loads
// (L1-bypass, L2-hit) under the unchanged LLC barrier protocol.
__global__ __launch_bounds__(512, 2) void k_main(
    const float* __restrict__ x, const int* __restrict__ mask,
    const float* __restrict__ Wh, const float* __restrict__ Wf,
    const float* __restrict__ bh, const float* __restrict__ bfr,
    const float* __restrict__ Wih, const float* __restrict__ Whh,
    const float* __restrict__ bih, const float* __restrict__ bhh,
    float* __restrict__ out, char* __restrict__ ws) {
  extern __shared__ char smem[];
  ushort_t* W_fr     = (ushort_t*)(smem + LDS_W);
  float* gates_lds   = (float*)(smem + LDS_GATES);
  float* bias_lds    = (float*)(smem + LDS_BIAS);
  float* xh_part     = (float*)(smem + LDS_XPART);
  float* xc_s        = (float*)(smem + LDS_XC);
  int*   misc        = (int*)(smem + LDS_MISC);

  unsigned* cnts = (unsigned*)(ws + OFF_FLAGS);
  const ushort_t* alpha = (const ushort_t*)(ws + OFF_ALPHA);
  const ushort_t* gh    = (const ushort_t*)(ws + OFF_GH);
  const ushort_t* mbf   = (const ushort_t*)(ws + OFF_MBF);
  float*    hws  = (float*)(ws + OFF_H);
  ushort_t* hdws = (ushort_t*)(ws + OFF_HDEC);
  ushort_t* ccbf = (ushort_t*)(ws + OFF_CCBF);

  const int tid = threadIdx.x;

  // ---- group = physical XCD; member = one-time slot within the XCD ----
  unsigned xcc;
  asm("s_getreg_b32 %0, hwreg(HW_REG_XCC_ID)" : "=s"(xcc));
  const int g = (int)(xcc & 7u);
  if (tid == 0) {
    // slot counter lives in an unused dword of group g's barrier-A line (zeroed by k_cvt)
    unsigned s = __hip_atomic_fetch_add(cnts + g * 64 + 16, 1u, __ATOMIC_RELAXED,
                                        __HIP_MEMORY_SCOPE_AGENT);
    misc[0] = (int)(s & 31u);
  }
  __syncthreads();
  const int mwg  = misc[0];          // member 0..31 (unique within XCD)
  const int ng   = mwg;              // gate col-block
  const int wave = tid >> 6, lane = tid & 63, quad = lane >> 4, lan = lane & 15;
  const int mt = wave & 3, khalf = wave >> 2;
  const int r0 = g * 64 + mwg * 2;   // phase1 rows
  const int arow = g * 64 + mt * 16 + lan;   // phase2 A-fragment batch row

  unsigned* cntA = cnts + (g * 2 + 0) * 32;
  unsigned* cntB = cnts + (g * 2 + 1) * 32;

  // ---- init: gate-weight slice -> fragment-packed LDS (bf16) ----
  for (int q = tid; q < 6144; q += 512) {
    int sec = q >> 10, rem = q & 1023;
    int f = rem >> 6, lw = rem & 63;
    int nt = f >> 2, kk = f & 3;
    int lan_ = lw & 15, quad_ = lw >> 4;
    int r = nt * 512 + ng * 16 + lan_;
    const float* src = (sec < 2)
        ? (Wih + (size_t)r * 256 + sec * 128 + kk * 32 + quad_ * 8)
        : (Whh + (size_t)r * 512 + (sec - 2) * 128 + kk * 32 + quad_ * 8);
    float4 v0 = *(const float4*)src;
    float4 v1 = *(const float4*)(src + 4);
    ushort_t t8[8] = { f2bf(v0.x), f2bf(v0.y), f2bf(v0.z), f2bf(v0.w),
                       f2bf(v1.x), f2bf(v1.y), f2bf(v1.z), f2bf(v1.w) };
    *(uint4*)&W_fr[q * 8] = *(const uint4*)t8;
  }
  if (tid < 64) {
    int r = (tid >> 4) * 512 + ng * 16 + (tid & 15);
    bias_lds[tid] = bih[r] + bhh[r];
  }

#define WFRAG(sec, nt, kk) (*(const bf16x8*)&W_fr[((((sec) * 16 + (nt) * 4 + (kk)) * 64 + lane)) * 8])

  // ---- init: Wh / Wf slices -> registers ----
  unsigned wh_p[64];
  {
    const float* s0 = Wh + (size_t)lane * HH + 64 * wave;
    const float* s1 = Wh + (size_t)(lane + 64) * HH + 64 * wave;
#pragma unroll
    for (int i4 = 0; i4 < 16; ++i4) {
      float4 a = *(const float4*)(s0 + i4 * 4);
      float4 b = *(const float4*)(s1 + i4 * 4);
      wh_p[i4 * 4 + 0] = ((unsigned)f2bf(a.x)) | (((unsigned)f2bf(b.x)) << 16);
      wh_p[i4 * 4 + 1] = ((unsigned)f2bf(a.y)) | (((unsigned)f2bf(b.y)) << 16);
      wh_p[i4 * 4 + 2] = ((unsigned)f2bf(a.z)) | (((unsigned)f2bf(b.z)) << 16);
      wh_p[i4 * 4 + 3] = ((unsigned)f2bf(a.w)) | (((unsigned)f2bf(b.w)) << 16);
    }
  }
  unsigned wf_p[16];
  {
    const float* s0 = Wf + (size_t)lane * FF + 16 * wave;
    const float* s1 = Wf + (size_t)(lane + 64) * FF + 16 * wave;
#pragma unroll
    for (int i4 = 0; i4 < 4; ++i4) {
      float4 a = *(const float4*)(s0 + i4 * 4);
      float4 b = *(const float4*)(s1 + i4 * 4);
      wf_p[i4 * 4 + 0] = ((unsigned)f2bf(a.x)) | (((unsigned)f2bf(b.x)) << 16);
      wf_p[i4 * 4 + 1] = ((unsigned)f2bf(a.y)) | (((unsigned)f2bf(b.y)) << 16);
      wf_p[i4 * 4 + 2] = ((unsigned)f2bf(a.z)) | (((unsigned)f2bf(b.z)) << 16);
      wf_p[i4 * 4 + 3] = ((unsigned)f2bf(a.w)) | (((unsigned)f2bf(b.w)) << 16);
    }
  }
  const int fdot = tid & 127;        // scalar-chain output index (tid<256 lanes)
  float bh_r = 0.f, bfr_r = 0.f, wfd_r = 0.f;
  if (tid < 256) {
    bh_r  = bh[fdot];
    bfr_r = bfr[fdot];
    wfd_r = bf2f(f2bf(Wf[(size_t)fdot * FF + fdot]));  // matches bf16 dot term exactly
  }

  // ---- init: zero owned state slices (buffer 0, plain stores -> XCD L2) ----
  const int b_l = tid >> 3, jl0 = 2 * (tid & 7);     // epilogue mapping
  const int bglob = g * 64 + b_l, j0 = ng * 16 + jl0;
  *(float2*)&hws[(size_t)bglob * HH + j0] = make_float2(0.f, 0.f);
  *(unsigned*)&hdws[(size_t)bglob * HH + j0] = 0u;
  float c_r0 = 0.f, c_r1 = 0.f;

  unsigned epA = 0, epB = 1;
  bar_arrive(cntB);

  for (int t = 0; t < TT; ++t) {
    // ---- prefetch step-indexed inputs (read-only, normal cached loads) ----
    float xv = 0.f, mv = 0.f, al = 0.f;
    if (tid < 256) {
      int bl = tid >> 7;
      int b = r0 + bl;
      size_t gix = (size_t)b * (TT * FF) + (size_t)t * FF + fdot;
      xv = x[gix];
      mv = (float)mask[gix];
      al = bf2f(alpha[((size_t)t * BB + b) * FF + fdot]);
    }
    unsigned gh2 = 0;
    if (t < TT - 1)
      gh2 = *(const unsigned*)&gh[((size_t)(t + 1) * BB + bglob) * HH + j0];
    bf16x8 A0[4], A1[4], A2[4];
    if (khalf == 0) {                                   // m-chunk: precomputed, cached
      const ushort_t* mrow = mbf + ((size_t)arow * TT + t) * FF + quad * 8;
#pragma unroll
      for (int kk = 0; kk < 4; ++kk) A0[kk] = *(const bf16x8*)(mrow + kk * 32);
    }

    // ---- wait for h/hdec of this step ----
    bar_wait(cntB, 32u * epB);

    // ---- sc0 loads (XCD L2): h one element/lane + hdec A-fragments (8/8 balanced) ----
    const float* hbuf = hws + (size_t)(t & 1) * BH;
    float h0r = ldf_l2(hbuf + (size_t)r0 * HH + 64 * wave + lane);
    float h1r = ldf_l2(hbuf + (size_t)(r0 + 1) * HH + 64 * wave + lane);
    {
      const ushort_t* hdec = hdws + (size_t)(t & 1) * BH;
      const ushort_t* hrow = hdec + (size_t)arow * HH + quad * 8;
      if (khalf == 0) {
#pragma unroll
        for (int kk = 0; kk < 4; ++kk) A1[kk] = ld16_l2(hrow + kk * 32);        // c0
#pragma unroll
        for (int kk = 0; kk < 4; ++kk) A2[kk] = ld16_l2(hrow + 128 + kk * 32);  // c1
      } else {
#pragma unroll
        for (int kk = 0; kk < 4; ++kk) A0[kk] = ld16_l2(hrow + 256 + kk * 32);  // c2
#pragma unroll
        for (int kk = 0; kk < 4; ++kk) A1[kk] = ld16_l2(hrow + 384 + kk * 32);  // c3
      }
    }
    waitvm0();

    // ---- phase2a MFMA (K-sections not depending on cc) ----
    f32x4 acc[4];
#pragma unroll
    for (int nt = 0; nt < 4; ++nt) acc[nt] = (f32x4){0.f, 0.f, 0.f, 0.f};
    if (khalf == 0) {
      // sections: m (sec1), hdec c0 (sec2), hdec c1 (sec3)
#pragma unroll
      for (int kk = 0; kk < 4; ++kk)
#pragma unroll
        for (int nt = 0; nt < 4; ++nt)
          acc[nt] = __builtin_amdgcn_mfma_f32_16x16x32_bf16(A0[kk], WFRAG(1, nt, kk), acc[nt], 0, 0, 0);
#pragma unroll
      for (int kk = 0; kk < 4; ++kk)
#pragma unroll
        for (int nt = 0; nt < 4; ++nt)
          acc[nt] = __builtin_amdgcn_mfma_f32_16x16x32_bf16(A1[kk], WFRAG(2, nt, kk), acc[nt], 0, 0, 0);
#pragma unroll
      for (int kk = 0; kk < 4; ++kk)
#pragma unroll
        for (int nt = 0; nt < 4; ++nt)
          acc[nt] = __builtin_amdgcn_mfma_f32_16x16x32_bf16(A2[kk], WFRAG(3, nt, kk), acc[nt], 0, 0, 0);
    } else {
      // sections: hdec c2 (sec4), hdec c3 (sec5)
#pragma unroll
      for (int kk = 0; kk < 4; ++kk)
#pragma unroll
        for (int nt = 0; nt < 4; ++nt)
          acc[nt] = __builtin_amdgcn_mfma_f32_16x16x32_bf16(A0[kk], WFRAG(4, nt, kk), acc[nt], 0, 0, 0);
#pragma unroll
      for (int kk = 0; kk < 4; ++kk)
#pragma unroll
        for (int nt = 0; nt < 4; ++nt)
          acc[nt] = __builtin_amdgcn_mfma_f32_16x16x32_bf16(A1[kk], WFRAG(5, nt, kk), acc[nt], 0, 0, 0);
      // khalf1 waves are done: publish partial gates now
#pragma unroll
      for (int nt = 0; nt < 4; ++nt)
#pragma unroll
        for (int r = 0; r < 4; ++r)
          gates_lds[(64 + mt * 16 + quad * 4 + r) * 68 + nt * 16 + lan] = acc[nt][r];
    }

    // ---- phase1: xh dot, VALU readlane broadcast ----
    {
      float a00 = 0.f, a01 = 0.f, a10 = 0.f, a11 = 0.f;
#pragma unroll
      for (int k = 0; k < 64; ++k) {
        float hk0 = rdlane_f(h0r, k);
        float hk1 = rdlane_f(h1r, k);
        unsigned wp = wh_p[k];
        float w0 = lo2f(wp), w1 = hi2f(wp);
        a00 = fmaf(w0, hk0, a00);
        a10 = fmaf(w1, hk0, a10);
        a01 = fmaf(w0, hk1, a01);
        a11 = fmaf(w1, hk1, a11);
      }
      xh_part[(wave * 2 + 0) * 128 + lane]      = a00;
      xh_part[(wave * 2 + 0) * 128 + 64 + lane] = a10;
      xh_part[(wave * 2 + 1) * 128 + lane]      = a01;
      xh_part[(wave * 2 + 1) * 128 + 64 + lane] = a11;
    }
    __syncthreads();

    float xh_r = 0.f;
    if (tid < 256) {
      int bl = tid >> 7;
      float s = bh_r;
#pragma unroll
      for (int w2 = 0; w2 < 8; ++w2) s += xh_part[(w2 * 2 + bl) * 128 + fdot];
      xh_r = s;
      float xcv = fmaf(1.0f - mv, xh_r, mv * xv);
      xc_s[bl * 128 + fdot] = xcv;
    }
    __syncthreads();

    // ---- z_h dot (same mapping, K-slice of 16 per wave) ----
    {
      float z00 = 0.f, z01 = 0.f, z10 = 0.f, z11 = 0.f;
      float x0 = xc_s[16 * wave + (lane & 15)];
      float x1 = xc_s[128 + 16 * wave + (lane & 15)];
#pragma unroll
      for (int k = 0; k < 16; ++k) {
        float xk0 = rdlane_f(x0, k);
        float xk1 = rdlane_f(x1, k);
        unsigned wp = wf_p[k];
        float w0 = lo2f(wp), w1 = hi2f(wp);
        z00 = fmaf(w0, xk0, z00);
        z10 = fmaf(w1, xk0, z10);
        z01 = fmaf(w0, xk1, z01);
        z11 = fmaf(w1, xk1, z11);
      }
      xh_part[(wave * 2 + 0) * 128 + lane]      = z00;
      xh_part[(wave * 2 + 0) * 128 + 64 + lane] = z10;
      xh_part[(wave * 2 + 1) * 128 + lane]      = z01;
      xh_part[(wave * 2 + 1) * 128 + 64 + lane] = z11;
    }
    __syncthreads();

    float zh = 0.f, ch = 0.f, cc = 0.f;
    if (tid < 256) {
      int bl = tid >> 7;
      int b = r0 + bl;
      float xcv = xc_s[bl * 128 + fdot];
      float s = bfr_r - xcv * wfd_r;
#pragma unroll
      for (int w2 = 0; w2 < 8; ++w2) s += xh_part[(w2 * 2 + bl) * 128 + fdot];
      zh = s;
      ch = fmaf(al, zh, (1.0f - al) * xh_r);
      cc = fmaf(1.0f - mv, ch, mv * xv);
      ccbf[b * FF + fdot] = f2bf(cc);          // plain store -> XCD L2, cross-WG consumed
    }

    // ---- barrier A arrive: cc published (drained at arrive's __syncthreads) ----
    bar_arrive(cntA); ++epA;

    // ---- out[] stores overlap barrier-A latency (host-only consumers) ----
    if (tid < 256) {
      int bl = tid >> 7;
      int b = r0 + bl;
      size_t ob = (size_t)b * (TT * FF) + (size_t)t * FF + fdot;
      out[ob] = cc;
      out[BTF + ob] = ch;
      out[2 * (size_t)BTF + ob] = zh;
      out[3 * (size_t)BTF + ob] = xh_r;
    }

    // ---- phase2b: khalf0 waves self-release on barrier A (per-wave poll) ----
    if (khalf == 0) {
      bar_wait_wave(cntA, 32u * epA, lane);
      const ushort_t* ccrow = ccbf + (size_t)arow * FF + quad * 8;
      bf16x8 AC[4];
#pragma unroll
      for (int kk = 0; kk < 4; ++kk) AC[kk] = ld16_l2(ccrow + kk * 32);
      waitvm0();
#pragma unroll
      for (int kk = 0; kk < 4; ++kk) {
#pragma unroll
        for (int nt = 0; nt < 4; ++nt) {
          acc[nt] = __builtin_amdgcn_mfma_f32_16x16x32_bf16(AC[kk], WFRAG(0, nt, kk), acc[nt], 0, 0, 0);
        }
      }
#pragma unroll
      for (int nt = 0; nt < 4; ++nt)
#pragma unroll
        for (int r = 0; r < 4; ++r)
          gates_lds[(mt * 16 + quad * 4 + r) * 68 + nt * 16 + lan] = acc[nt][r];
    }
    __syncthreads();

    // ---- LSTM epilogue: c in registers, write h (f32) + pre-decayed h (bf16), plain ----
    {
      const float* g0 = &gates_lds[(size_t)b_l * 68 + jl0];
      const float* g1 = &gates_lds[(size_t)(64 + b_l) * 68 + jl0];
      float2 gI = make_float2(g0[0] + g1[0] + bias_lds[jl0],
                              g0[1] + g1[1] + bias_lds[jl0 + 1]);
      float2 gF = make_float2(g0[16] + g1[16] + bias_lds[16 + jl0],
                              g0[17] + g1[17] + bias_lds[16 + jl0 + 1]);
      float2 gG = make_float2(g0[32] + g1[32] + bias_lds[32 + jl0],
                              g0[33] + g1[33] + bias_lds[32 + jl0 + 1]);
      float2 gO = make_float2(g0[48] + g1[48] + bias_lds[48 + jl0],
                              g0[49] + g1[49] + bias_lds[48 + jl0 + 1]);
      c_r0 = fmaf(sigm(gF.x), c_r0, sigm(gI.x) * tanhf(gG.x));
      c_r1 = fmaf(sigm(gF.y), c_r1, sigm(gI.y) * tanhf(gG.y));
      float h0 = sigm(gO.x) * tanhf(c_r0);
      float h1 = sigm(gO.y) * tanhf(c_r1);
      float* hwN = hws + (size_t)((t + 1) & 1) * BH;
      ushort_t* hdN = hdws + (size_t)((t + 1) & 1) * BH;
      *(float2*)&hwN[(size_t)bglob * HH + j0] = make_float2(h0, h1);
      float gHa = lo2f(gh2), gHb = hi2f(gh2);
      unsigned hp = ((unsigned)f2bf(h0 * gHa)) | (((unsigned)f2bf(h1 * gHb)) << 16);
      *(unsigned*)&hdN[(size_t)bglob * HH + j0] = hp;
    }

    // ---- barrier B arrive: h / hdec published ----
    bar_arrive(cntB); ++epB;
  }
#undef WFRAG
}

// ---------------- host ----------------
extern "C" void kernel_launch(void* const* d_in, const int* in_sizes, int n_in,
                              void* d_out, int out_size, void* d_ws, size_t ws_size,
                              hipStream_t stream) {
  (void)in_sizes; (void)n_in; (void)out_size; (void)ws_size;
  const float* x   = (const float*)d_in[0];
  const int*   mask= (const int*)d_in[1];
  const float* Wdh = (const float*)d_in[2];
  const float* bdh = (const float*)d_in[3];
  const float* Wdx = (const float*)d_in[4];
  const float* bdx = (const float*)d_in[5];
  const float* Wh  = (const float*)d_in[6];
  const float* bh  = (const float*)d_in[7];
  const float* Wf  = (const float*)d_in[8];
  const float* bfr = (const float*)d_in[9];
  const float* Wc  = (const float*)d_in[10];
  const float* bc  = (const float*)d_in[11];
  const float* Wih = (const float*)d_in[12];
  const float* Whh = (const float*)d_in[13];
  const float* bih = (const float*)d_in[14];
  const float* bhh = (const float*)d_in[15];
  float* out = (float*)d_out;
  char* ws = (char*)d_ws;

  hipLaunchKernelGGL(k_cvt,  dim3(1),   dim3(256), 0, stream, Wdx, ws);
  hipLaunchKernelGGL(k_prep, dim3(256), dim3(256), 0, stream, mask, ws);
  hipLaunchKernelGGL(k_gh,   dim3(768, 8), dim3(256), 0, stream, Wdh, bdh, ws);
  hipLaunchKernelGGL(k_al,   dim3(768, 2), dim3(256), 0, stream, Wc, bc, bdx, ws);

  hipFuncSetAttribute((const void*)k_main, hipFuncAttributeMaxDynamicSharedMemorySize, LDS_TOTAL);
  void* args[] = { (void*)&x, (void*)&mask, (void*)&Wh, (void*)&Wf, (void*)&bh, (void*)&bfr,
                   (void*)&Wih, (void*)&Whh, (void*)&bih, (void*)&bhh, (void*)&out, (void*)&ws };
  hipLaunchCooperativeKernel((const void*)k_main, dim3(256), dim3(512), args, LDS_TOTAL, stream);
}